// Round 3
// baseline (890.649 us; speedup 1.0000x reference)
//
#include <hip/hip_runtime.h>
#include <stdint.h>

#define DIM     1280
#define NHEADS  16
#define HD      80
#define NV      16
#define MAXP    1024
#define MTOT    (NV*MAXP)   // 16384

typedef __bf16 bf16;
using bf16x8 = __attribute__((ext_vector_type(8))) __bf16;
using bf16x4 = __attribute__((ext_vector_type(4))) __bf16;
using f32x4  = __attribute__((ext_vector_type(4))) float;

#define GLOAD_LDS16(g, l)                                                     \
    __builtin_amdgcn_global_load_lds(                                         \
        (const __attribute__((address_space(1))) void*)(g),                   \
        (__attribute__((address_space(3))) void*)(l), 16, 0, 0)

// ---------------------------------------------------------------------------
// fp32 -> bf16 bulk convert (vectorized, n must be a multiple of 4)
// ---------------------------------------------------------------------------
__global__ __launch_bounds__(256)
void cvt_bf16(const float* __restrict__ src, bf16* __restrict__ dst, int n4)
{
    const int i = blockIdx.x * 256 + threadIdx.x;
    if (i < n4) {
        const float4 f = ((const float4*)src)[i];
        bf16x4 r;
        r[0] = (bf16)f.x; r[1] = (bf16)f.y; r[2] = (bf16)f.z; r[3] = (bf16)f.w;
        ((bf16x4*)dst)[i] = r;
    }
}

// ---------------------------------------------------------------------------
// m97-structure NT GEMM with XOR-swizzled LDS + XCD-chunked swizzle.
// (unchanged this round)
// ---------------------------------------------------------------------------
template<bool IS_QKV, int NB, int G>
__global__ __launch_bounds__(256)
void gemm_nt_big(const bf16* __restrict__ A, const bf16* __restrict__ B,
                 const float* __restrict__ bias,
                 bf16* __restrict__ out0, bf16* __restrict__ out1,
                 bf16* __restrict__ out2, float* __restrict__ outf)
{
    const int K = DIM;
    __shared__ __align__(16) bf16 SH[2*128*64];   // As | Bs ; reused as C-tile
    bf16* const As = SH;
    bf16* const Bs = SH + 128*64;

    const int tid  = threadIdx.x;
    const int lane = tid & 63, wave = tid >> 6;
    const int quad = lane >> 4, c16 = lane & 15;
    const int wm = wave & 1, wn = wave >> 1;

    // XCD-chunked block swizzle (bijective: grid = 8 * 16 * NB)
    const int bid = blockIdx.x;
    const int xcd = bid & 7;
    const int idx = bid >> 3;
    const int nbg = idx / (16*G);
    const int rem = idx % (16*G);
    const int mb  = xcd*16 + rem / G;
    const int nb  = nbg*G  + rem % G;

    const int sr   = lane >> 3;
    const int slot = lane & 7;
    const int sc   = (slot ^ sr) * 8;
    const long a_row0 = (long)mb * 128;
    const long b_row0 = (long)nb * 128;

    const bf16* ga[4];
    const bf16* gb[4];
    #pragma unroll
    for (int c = 0; c < 4; ++c) {
        const int seg = c*4 + wave;
        const int row = seg*8 + sr;
        ga[c] = A + (a_row0 + row)*K + sc;
        gb[c] = B + (b_row0 + row)*K + sc;
    }

    f32x4 acc[4][4] = {};
    const int xr = c16 & 7;

    for (int kt = 0; kt < K/64; ++kt) {
        const int k0 = kt * 64;
        __syncthreads();
        #pragma unroll
        for (int c = 0; c < 4; ++c) {
            const int seg = c*4 + wave;
            GLOAD_LDS16(ga[c] + k0, As + seg*512);
            GLOAD_LDS16(gb[c] + k0, Bs + seg*512);
        }
        __syncthreads();
        #pragma unroll
        for (int kk = 0; kk < 2; ++kk) {
            const int j  = kk*4 + quad;
            const int ko = ((j ^ xr) * 8);
            bf16x8 af[4], bfr[4];
            #pragma unroll
            for (int mt = 0; mt < 4; ++mt)
                af[mt] = *(const bf16x8*)(As + (wm*64 + mt*16 + c16)*64 + ko);
            #pragma unroll
            for (int nt = 0; nt < 4; ++nt)
                bfr[nt] = *(const bf16x8*)(Bs + (wn*64 + nt*16 + c16)*64 + ko);
            #pragma unroll
            for (int mt = 0; mt < 4; ++mt)
                #pragma unroll
                for (int nt = 0; nt < 4; ++nt)
                    acc[mt][nt] = __builtin_amdgcn_mfma_f32_16x16x32_bf16(
                        af[mt], bfr[nt], acc[mt][nt], 0, 0, 0);
        }
    }

    if constexpr (IS_QKV) {
        const int which = nb / 10;               // block-uniform (128 | 1280)
        if (which < 2) {
            bf16* const dst = (which == 0) ? out0 : out1;
            #pragma unroll
            for (int nt = 0; nt < 4; ++nt) {
                const int col = nb*128 + wn*64 + nt*16 + c16;
                const float bv = bias[col];
                const int rr = col - which*DIM;
                const int h  = rr / HD;
                const int d  = rr - h*HD;
                #pragma unroll
                for (int mt = 0; mt < 4; ++mt) {
                    #pragma unroll
                    for (int r = 0; r < 4; ++r) {
                        const int row = mb*128 + wm*64 + mt*16 + quad*4 + r;
                        const int n = row >> 10, p = row & 1023;
                        dst[((long)((n*NHEADS + h)*MAXP + p))*HD + d] =
                            (bf16)(acc[mt][nt][r] + bv);
                    }
                }
            }
        } else {
            // v^T: stage C-tile into LDS as VT[d][p ^ ((d&15)<<3)], then
            // coalesced 16B stores along p.
            __syncthreads();                     // K-loop LDS reads done
            #pragma unroll
            for (int nt = 0; nt < 4; ++nt) {
                const int dl0 = wn*64 + nt*16 + c16;       // local d 0..127
                const float bv = bias[nb*128 + dl0];
                const int swz = (dl0 & 15) << 3;
                #pragma unroll
                for (int mt = 0; mt < 4; ++mt) {
                    #pragma unroll
                    for (int r = 0; r < 4; ++r) {
                        const int pl = wm*64 + mt*16 + quad*4 + r;
                        SH[dl0*128 + (pl ^ swz)] = (bf16)(acc[mt][nt][r] + bv);
                    }
                }
            }
            __syncthreads();
            const int n_    = mb >> 3;
            const int pbase = (mb & 7) * 128;
            #pragma unroll
            for (int it = 0; it < 8; ++it) {
                const int c  = tid + 256*it;     // 0..2047
                const int dl = c >> 4, j = c & 15;
                const int p0 = (j ^ (dl & 15)) << 3;
                const int rr = (nb - 20)*128 + dl;
                const int hh = rr / HD;
                const int dd = rr - hh*HD;
                bf16x8 v = *(const bf16x8*)(SH + dl*128 + j*8);
                *(bf16x8*)(out2 + ((long)((n_*NHEADS + hh)*HD + dd))*MAXP
                                  + pbase + p0) = v;
            }
        }
    } else {
        #pragma unroll
        for (int nt = 0; nt < 4; ++nt) {
            const int col = nb*128 + wn*64 + nt*16 + c16;
            const float bv = bias[col];
            #pragma unroll
            for (int mt = 0; mt < 4; ++mt) {
                #pragma unroll
                for (int r = 0; r < 4; ++r) {
                    const int row = mb*128 + wm*64 + mt*16 + quad*4 + r;
                    outf[(long)row*DIM + col] = acc[mt][nt][r] + bv;
                }
            }
        }
    }
}

// ---------------------------------------------------------------------------
// RoPE in-place on q,k — vectorized (unchanged this round)
// ---------------------------------------------------------------------------
__global__ __launch_bounds__(320)
void rope_kernel(bf16* __restrict__ qb, bf16* __restrict__ kb,
                 const float* __restrict__ rope)
{
    const int tid = threadIdx.x;
    const int j   = tid % 5;
    const int rl  = tid / 5;
    const long grow = (long)blockIdx.x * 64 + rl;
    const int p = (int)(grow & 1023);
    const int h = (int)((grow >> 10) & 15);
    const int n = (int)((grow >> 14) & 15);
    const int a = (int)(grow >> 18);
    bf16* const arr = a ? kb : qb;
    const long base = ((long)((n*NHEADS + h)*MAXP + p))*HD;
    const float* rc = rope + ((long)(n*MAXP + p))*160;
    const int d = j*8;

    bf16x8 x1v = *(const bf16x8*)(arr + base + d);
    bf16x8 x2v = *(const bf16x8*)(arr + base + 40 + d);

    float c1[8], s1[8], c2[8], s2[8];
    *(float4*)(c1)   = *(const float4*)(rc + d);
    *(float4*)(c1+4) = *(const float4*)(rc + d + 4);
    *(float4*)(s1)   = *(const float4*)(rc + 80 + d);
    *(float4*)(s1+4) = *(const float4*)(rc + 80 + d + 4);
    *(float4*)(c2)   = *(const float4*)(rc + 40 + d);
    *(float4*)(c2+4) = *(const float4*)(rc + 40 + d + 4);
    *(float4*)(s2)   = *(const float4*)(rc + 120 + d);
    *(float4*)(s2+4) = *(const float4*)(rc + 120 + d + 4);

    const float QS = 0.11180339887498949f * 1.4426950408889634f;
    bf16x8 r1, r2;
    #pragma unroll
    for (int i = 0; i < 8; ++i) {
        const float x1 = (float)x1v[i];
        const float x2 = (float)x2v[i];
        float o1 = x1 * c1[i] - x2 * s1[i];
        float o2 = x2 * c2[i] + x1 * s2[i];
        if (a == 0) { o1 *= QS; o2 *= QS; }
        r1[i] = (bf16)o1;
        r2[i] = (bf16)o2;
    }
    *(bf16x8*)(arr + base + d)      = r1;
    *(bf16x8*)(arr + base + 40 + d) = r2;
}

// ---------------------------------------------------------------------------
// Flash attention, swapped-operand form. NEW this round:
//   - T14 async-stage: next tile's K/V global loads issued into regs right
//     after the LDS-ready barrier; committed to LDS at top of next iter.
//   - mask only on the last K-tile (wave-uniform branch).
//   - T13 defer-max (THR=8, exp2 domain): skip O-rescale when the tile max
//     didn't grow past mrow+8; P bounded by 2^8, f32 accum — safe.
//   - T5 setprio around QK and PV MFMA clusters.
// ---------------------------------------------------------------------------
__global__ __launch_bounds__(256)
void attn_kernel(const bf16* __restrict__ qb, const bf16* __restrict__ kb,
                 const bf16* __restrict__ vt, const int* __restrict__ seq_lens,
                 bf16* __restrict__ outb)
{
    __shared__ __align__(16) bf16 Qs[64*104];    // stride 104 bf16 = 208 B
    __shared__ __align__(16) bf16 Ks[64*104];
    __shared__ __align__(16) bf16 Vts[80*72];    // V^T: [d][key], stride 144 B

    const int tid  = threadIdx.x;
    const int lane = tid & 63, wave = tid >> 6;
    const int quad = lane >> 4, c16 = lane & 15;
    const int qt = blockIdx.x, h = blockIdx.y, n = blockIdx.z;
    const int seqlen = seq_lens[n];

    const long qkbase = ((long)(n*NHEADS + h)) * MAXP * HD;
    const long vbase  = ((long)(n*NHEADS + h)) * HD * MAXP;

    const float4 zero4 = make_float4(0.f, 0.f, 0.f, 0.f);

    // per-thread staging geometry (loop-invariant)
    int krow[3], kcc[3];
    #pragma unroll
    for (int j = 0; j < 3; ++j) {
        const int i = tid + 256*j;
        krow[j] = i / 12; kcc[j] = i % 12;
    }
    const int vd0 = tid >> 3;
    const int vd1 = (tid + 256) >> 3;
    const int vd2 = (tid + 512) >> 3;
    const int vc  = tid & 7;
    const bool v2ok = tid < 128;

    float4 kreg[3], vreg[3];
    auto issue = [&](int ktp) {
        #pragma unroll
        for (int j = 0; j < 3; ++j)
            kreg[j] = (kcc[j] < 10)
                ? *(const float4*)(kb + qkbase + (long)(ktp*64 + krow[j])*HD + kcc[j]*8)
                : zero4;
        vreg[0] = *(const float4*)(vt + vbase + (long)vd0*MAXP + ktp*64 + vc*8);
        vreg[1] = *(const float4*)(vt + vbase + (long)vd1*MAXP + ktp*64 + vc*8);
        if (v2ok)
            vreg[2] = *(const float4*)(vt + vbase + (long)vd2*MAXP + ktp*64 + vc*8);
    };
    auto commit = [&]() {
        #pragma unroll
        for (int j = 0; j < 3; ++j)
            *(float4*)(Ks + krow[j]*104 + kcc[j]*8) = kreg[j];
        *(float4*)(Vts + vd0*72 + vc*8) = vreg[0];
        *(float4*)(Vts + vd1*72 + vc*8) = vreg[1];
        if (v2ok) *(float4*)(Vts + vd2*72 + vc*8) = vreg[2];
    };

    // prologue: issue first K/V tile, stage Q
    issue(0);
    for (int i = tid; i < 768; i += 256) {       // 64 rows x 12 chunks of 16B
        int row = i / 12, c = i % 12;
        float4 v = (c < 10)
            ? *(const float4*)(qb + qkbase + (long)(qt*64 + row)*HD + c*8)
            : zero4;
        *(float4*)(Qs + row*104 + c*8) = v;
    }
    __syncthreads();
    bf16x8 aq[3];                                // Q as B-fragment (n = own q)
    #pragma unroll
    for (int kc = 0; kc < 3; ++kc)
        aq[kc] = *(const bf16x8*)(Qs + (wave*16 + c16)*104 + kc*32 + quad*8);

    float mrow = -1e30f, lrow = 0.0f;
    f32x4 O[5] = {};                             // O^T[d = dt*16+quad*4+r][q=c16]

    union U8 { bf16x8 v; bf16x4 h[2]; };

    const int nkt = (seqlen + 63) >> 6;
    for (int kt = 0; kt < nkt; ++kt) {
        __syncthreads();                         // prev tile's LDS reads done
        commit();
        __syncthreads();                         // LDS ready
        if (kt + 1 < nkt) issue(kt + 1);         // overlap next loads w/ compute

        // S^T = K * Q^T : A = K rows (m = key), B = Q (n = q)
        f32x4 S[4] = {};
        __builtin_amdgcn_s_setprio(1);
        #pragma unroll
        for (int kc = 0; kc < 3; ++kc) {
            const int ko = kc*32 + quad*8;
            #pragma unroll
            for (int nt = 0; nt < 4; ++nt) {
                bf16x8 ak = *(const bf16x8*)(Ks + (nt*16 + c16)*104 + ko);
                S[nt] = __builtin_amdgcn_mfma_f32_16x16x32_bf16(ak, aq[kc], S[nt], 0,0,0);
            }
        }
        __builtin_amdgcn_s_setprio(0);

        if (kt == nkt - 1) {                     // mask only on last tile
            #pragma unroll
            for (int nt = 0; nt < 4; ++nt) {
                const int key0 = kt*64 + nt*16 + quad*4;
                #pragma unroll
                for (int r = 0; r < 4; ++r)
                    if (key0 + r >= seqlen) S[nt][r] = -1e30f;
            }
        }

        // in-lane max tree (16 values) + 2 cross-quad shuffles
        float mx[4];
        #pragma unroll
        for (int nt = 0; nt < 4; ++nt)
            mx[nt] = fmaxf(fmaxf(S[nt][0], S[nt][1]), fmaxf(S[nt][2], S[nt][3]));
        float pmax = fmaxf(fmaxf(mx[0], mx[1]), fmaxf(mx[2], mx[3]));
        pmax = fmaxf(pmax, __shfl_xor(pmax, 16));
        pmax = fmaxf(pmax, __shfl_xor(pmax, 32));

        // T13 defer-max: only rescale when the max grew past mrow+8
        if (!__all(pmax <= mrow + 8.0f)) {
            const float nm    = fmaxf(mrow, pmax);
            const float alpha = exp2f(mrow - nm);
            mrow = nm;
            lrow *= alpha;
            #pragma unroll
            for (int dt = 0; dt < 5; ++dt)
                #pragma unroll
                for (int r = 0; r < 4; ++r)
                    O[dt][r] *= alpha;
        }

        #pragma unroll
        for (int nt = 0; nt < 4; ++nt)
            #pragma unroll
            for (int r = 0; r < 4; ++r)
                S[nt][r] = exp2f(S[nt][r] - mrow);

        float sm[4];
        #pragma unroll
        for (int nt = 0; nt < 4; ++nt)
            sm[nt] = (S[nt][0] + S[nt][1]) + (S[nt][2] + S[nt][3]);
        float rs = (sm[0] + sm[1]) + (sm[2] + sm[3]);
        rs += __shfl_xor(rs, 16);
        rs += __shfl_xor(rs, 32);
        lrow += rs;

        // pack P (lane-local): B-frag for PV kc = [pf[2kc][0..3], pf[2kc+1][0..3]]
        bf16x8 Pk[2];
        #pragma unroll
        for (int nt = 0; nt < 4; ++nt)
            #pragma unroll
            for (int r = 0; r < 4; ++r)
                Pk[nt >> 1][(nt & 1)*4 + r] = (bf16)S[nt][r];

        // O^T += V^T * P^T with key order kappa(kc,quad,j)
        __builtin_amdgcn_s_setprio(1);
        #pragma unroll
        for (int kc = 0; kc < 2; ++kc) {
            #pragma unroll
            for (int dt = 0; dt < 5; ++dt) {
                U8 av;
                av.h[0] = *(const bf16x4*)(Vts + (dt*16 + c16)*72 + kc*32 + quad*4);
                av.h[1] = *(const bf16x4*)(Vts + (dt*16 + c16)*72 + kc*32 + 16 + quad*4);
                O[dt] = __builtin_amdgcn_mfma_f32_16x16x32_bf16(av.v, Pk[kc], O[dt], 0,0,0);
            }
        }
        __builtin_amdgcn_s_setprio(0);
    }

    // epilogue: normalize, transpose O^T -> O through Qs (dead), coalesced store
    const float inv = 1.0f / lrow;
    #pragma unroll
    for (int dt = 0; dt < 5; ++dt)
        #pragma unroll
        for (int r = 0; r < 4; ++r)
            Qs[(wave*16 + c16)*104 + dt*16 + quad*4 + r] = (bf16)(O[dt][r] * inv);
    __syncthreads();
    for (int i = tid; i < 640; i += 256) {       // 64 rows x 10 chunks of 16B
        const int row = i / 10, c = i % 10;
        const float4 v = *(const float4*)(Qs + row*104 + c*8);
        *(float4*)(outb + ((long)(n*MAXP + qt*64 + row))*DIM + h*HD + c*8) = v;
    }
}

// ---------------------------------------------------------------------------
// Buffer plan:
//   d_ws   : hidden_bf (42 MB) | wqkv_bf (9.8 MB) | wproj_bf (3.3 MB)
//   d_out  : q (42 MB bf16) | k (42 MB bf16)  — overwritten by proj fp32 at end
//   d_in[0]: vT (42 MB bf16) | attn_out (42 MB bf16) — hidden fp32 dead after cvt
// ---------------------------------------------------------------------------
extern "C" void kernel_launch(void* const* d_in, const int* in_sizes, int n_in,
                              void* d_out, int out_size, void* d_ws, size_t ws_size,
                              hipStream_t stream)
{
    const float* hidden = (const float*)d_in[0];
    const float* rope   = (const float*)d_in[1];
    const int*   seql   = (const int*)d_in[2];
    const float* wqkv   = (const float*)d_in[3];
    const float* bqkv   = (const float*)d_in[4];
    const float* wproj  = (const float*)d_in[5];
    const float* bproj  = (const float*)d_in[6];
    float* out = (float*)d_out;

    const size_t H_ELEMS  = (size_t)MTOT*DIM;          // 20,971,520
    const size_t WQ_ELEMS = (size_t)3*DIM*DIM;         //  4,915,200
    const size_t WP_ELEMS = (size_t)DIM*DIM;           //  1,638,400
    const size_t QK_ELEMS = (size_t)NV*NHEADS*MAXP*HD; // 20,971,520

    bf16* h_bf  = (bf16*)d_ws;
    bf16* wq_bf = h_bf  + H_ELEMS;
    bf16* wp_bf = wq_bf + WQ_ELEMS;

    bf16* q_b = (bf16*)d_out;
    bf16* k_b = q_b + QK_ELEMS;
    bf16* v_t = (bf16*)d_in[0];
    bf16* a_b = v_t + QK_ELEMS;

    cvt_bf16<<<(H_ELEMS/4 + 255)/256, 256, 0, stream>>>(hidden, h_bf, H_ELEMS/4);
    cvt_bf16<<<(WQ_ELEMS/4 + 255)/256, 256, 0, stream>>>(wqkv, wq_bf, WQ_ELEMS/4);
    cvt_bf16<<<(WP_ELEMS/4 + 255)/256, 256, 0, stream>>>(wproj, wp_bf, WP_ELEMS/4);

    // QKV: grid = 8 XCD * 16 mb * 30 nb = 3840 ; G=6 (B group 1.9 MB in L2)
    gemm_nt_big<true, 30, 6><<<3840, 256, 0, stream>>>(
        h_bf, wq_bf, bqkv, q_b, k_b, v_t, nullptr);

    // rows = 2*16*16*1024 = 524288 ; 64 rows/block, 320 threads
    rope_kernel<<<524288/64, 320, 0, stream>>>(q_b, k_b, rope);

    attn_kernel<<<dim3(MAXP/64, NHEADS, NV), 256, 0, stream>>>(
        q_b, k_b, v_t, seql, a_b);

    // proj: grid = 8 * 16 * 10 = 1280 ; G=10 (whole wproj 3.3 MB in L2)
    gemm_nt_big<false, 10, 10><<<1280, 256, 0, stream>>>(
        a_b, wp_bf, bproj, nullptr, nullptr, nullptr, out);
}

// Round 4
// 657.249 us; speedup vs baseline: 1.3551x; 1.3551x over previous
//
#include <hip/hip_runtime.h>
#include <stdint.h>

#define DIM     1280
#define NHEADS  16
#define HD      80
#define NV      16
#define MAXP    1024
#define MTOT    (NV*MAXP)   // 16384

typedef __bf16 bf16;
using bf16x8 = __attribute__((ext_vector_type(8))) __bf16;
using bf16x4 = __attribute__((ext_vector_type(4))) __bf16;
using f32x4  = __attribute__((ext_vector_type(4))) float;

#define GLOAD_LDS16(g, l)                                                     \
    __builtin_amdgcn_global_load_lds(                                         \
        (const __attribute__((address_space(1))) void*)(g),                   \
        (__attribute__((address_space(3))) void*)(l), 16, 0, 0)

// ---------------------------------------------------------------------------
// fp32 -> bf16 bulk convert (vectorized, n must be a multiple of 4)
// ---------------------------------------------------------------------------
__global__ __launch_bounds__(256)
void cvt_bf16(const float* __restrict__ src, bf16* __restrict__ dst, int n4)
{
    const int i = blockIdx.x * 256 + threadIdx.x;
    if (i < n4) {
        const float4 f = ((const float4*)src)[i];
        bf16x4 r;
        r[0] = (bf16)f.x; r[1] = (bf16)f.y; r[2] = (bf16)f.z; r[3] = (bf16)f.w;
        ((bf16x4*)dst)[i] = r;
    }
}

// ---------------------------------------------------------------------------
// m97-structure NT GEMM with XOR-swizzled LDS + XCD-chunked swizzle.
// (unchanged this round)
// ---------------------------------------------------------------------------
template<bool IS_QKV, int NB, int G>
__global__ __launch_bounds__(256)
void gemm_nt_big(const bf16* __restrict__ A, const bf16* __restrict__ B,
                 const float* __restrict__ bias,
                 bf16* __restrict__ out0, bf16* __restrict__ out1,
                 bf16* __restrict__ out2, float* __restrict__ outf)
{
    const int K = DIM;
    __shared__ __align__(16) bf16 SH[2*128*64];   // As | Bs ; reused as C-tile
    bf16* const As = SH;
    bf16* const Bs = SH + 128*64;

    const int tid  = threadIdx.x;
    const int lane = tid & 63, wave = tid >> 6;
    const int quad = lane >> 4, c16 = lane & 15;
    const int wm = wave & 1, wn = wave >> 1;

    // XCD-chunked block swizzle (bijective: grid = 8 * 16 * NB)
    const int bid = blockIdx.x;
    const int xcd = bid & 7;
    const int idx = bid >> 3;
    const int nbg = idx / (16*G);
    const int rem = idx % (16*G);
    const int mb  = xcd*16 + rem / G;
    const int nb  = nbg*G  + rem % G;

    const int sr   = lane >> 3;
    const int slot = lane & 7;
    const int sc   = (slot ^ sr) * 8;
    const long a_row0 = (long)mb * 128;
    const long b_row0 = (long)nb * 128;

    const bf16* ga[4];
    const bf16* gb[4];
    #pragma unroll
    for (int c = 0; c < 4; ++c) {
        const int seg = c*4 + wave;
        const int row = seg*8 + sr;
        ga[c] = A + (a_row0 + row)*K + sc;
        gb[c] = B + (b_row0 + row)*K + sc;
    }

    f32x4 acc[4][4] = {};
    const int xr = c16 & 7;

    for (int kt = 0; kt < K/64; ++kt) {
        const int k0 = kt * 64;
        __syncthreads();
        #pragma unroll
        for (int c = 0; c < 4; ++c) {
            const int seg = c*4 + wave;
            GLOAD_LDS16(ga[c] + k0, As + seg*512);
            GLOAD_LDS16(gb[c] + k0, Bs + seg*512);
        }
        __syncthreads();
        #pragma unroll
        for (int kk = 0; kk < 2; ++kk) {
            const int j  = kk*4 + quad;
            const int ko = ((j ^ xr) * 8);
            bf16x8 af[4], bfr[4];
            #pragma unroll
            for (int mt = 0; mt < 4; ++mt)
                af[mt] = *(const bf16x8*)(As + (wm*64 + mt*16 + c16)*64 + ko);
            #pragma unroll
            for (int nt = 0; nt < 4; ++nt)
                bfr[nt] = *(const bf16x8*)(Bs + (wn*64 + nt*16 + c16)*64 + ko);
            #pragma unroll
            for (int mt = 0; mt < 4; ++mt)
                #pragma unroll
                for (int nt = 0; nt < 4; ++nt)
                    acc[mt][nt] = __builtin_amdgcn_mfma_f32_16x16x32_bf16(
                        af[mt], bfr[nt], acc[mt][nt], 0, 0, 0);
        }
    }

    if constexpr (IS_QKV) {
        const int which = nb / 10;               // block-uniform (128 | 1280)
        if (which < 2) {
            bf16* const dst = (which == 0) ? out0 : out1;
            #pragma unroll
            for (int nt = 0; nt < 4; ++nt) {
                const int col = nb*128 + wn*64 + nt*16 + c16;
                const float bv = bias[col];
                const int rr = col - which*DIM;
                const int h  = rr / HD;
                const int d  = rr - h*HD;
                #pragma unroll
                for (int mt = 0; mt < 4; ++mt) {
                    #pragma unroll
                    for (int r = 0; r < 4; ++r) {
                        const int row = mb*128 + wm*64 + mt*16 + quad*4 + r;
                        const int n = row >> 10, p = row & 1023;
                        dst[((long)((n*NHEADS + h)*MAXP + p))*HD + d] =
                            (bf16)(acc[mt][nt][r] + bv);
                    }
                }
            }
        } else {
            // v^T: stage C-tile into LDS as VT[d][p ^ ((d&15)<<3)], then
            // coalesced 16B stores along p.
            __syncthreads();                     // K-loop LDS reads done
            #pragma unroll
            for (int nt = 0; nt < 4; ++nt) {
                const int dl0 = wn*64 + nt*16 + c16;       // local d 0..127
                const float bv = bias[nb*128 + dl0];
                const int swz = (dl0 & 15) << 3;
                #pragma unroll
                for (int mt = 0; mt < 4; ++mt) {
                    #pragma unroll
                    for (int r = 0; r < 4; ++r) {
                        const int pl = wm*64 + mt*16 + quad*4 + r;
                        SH[dl0*128 + (pl ^ swz)] = (bf16)(acc[mt][nt][r] + bv);
                    }
                }
            }
            __syncthreads();
            const int n_    = mb >> 3;
            const int pbase = (mb & 7) * 128;
            #pragma unroll
            for (int it = 0; it < 8; ++it) {
                const int c  = tid + 256*it;     // 0..2047
                const int dl = c >> 4, j = c & 15;
                const int p0 = (j ^ (dl & 15)) << 3;
                const int rr = (nb - 20)*128 + dl;
                const int hh = rr / HD;
                const int dd = rr - hh*HD;
                bf16x8 v = *(const bf16x8*)(SH + dl*128 + j*8);
                *(bf16x8*)(out2 + ((long)((n_*NHEADS + hh)*HD + dd))*MAXP
                                  + pbase + p0) = v;
            }
        }
    } else {
        #pragma unroll
        for (int nt = 0; nt < 4; ++nt) {
            const int col = nb*128 + wn*64 + nt*16 + c16;
            const float bv = bias[col];
            #pragma unroll
            for (int mt = 0; mt < 4; ++mt) {
                #pragma unroll
                for (int r = 0; r < 4; ++r) {
                    const int row = mb*128 + wm*64 + mt*16 + quad*4 + r;
                    outf[(long)row*DIM + col] = acc[mt][nt][r] + bv;
                }
            }
        }
    }
}

// ---------------------------------------------------------------------------
// RoPE in-place on q,k — vectorized (unchanged this round)
// ---------------------------------------------------------------------------
__global__ __launch_bounds__(320)
void rope_kernel(bf16* __restrict__ qb, bf16* __restrict__ kb,
                 const float* __restrict__ rope)
{
    const int tid = threadIdx.x;
    const int j   = tid % 5;
    const int rl  = tid / 5;
    const long grow = (long)blockIdx.x * 64 + rl;
    const int p = (int)(grow & 1023);
    const int h = (int)((grow >> 10) & 15);
    const int n = (int)((grow >> 14) & 15);
    const int a = (int)(grow >> 18);
    bf16* const arr = a ? kb : qb;
    const long base = ((long)((n*NHEADS + h)*MAXP + p))*HD;
    const float* rc = rope + ((long)(n*MAXP + p))*160;
    const int d = j*8;

    bf16x8 x1v = *(const bf16x8*)(arr + base + d);
    bf16x8 x2v = *(const bf16x8*)(arr + base + 40 + d);

    float c1[8], s1[8], c2[8], s2[8];
    *(float4*)(c1)   = *(const float4*)(rc + d);
    *(float4*)(c1+4) = *(const float4*)(rc + d + 4);
    *(float4*)(s1)   = *(const float4*)(rc + 80 + d);
    *(float4*)(s1+4) = *(const float4*)(rc + 80 + d + 4);
    *(float4*)(c2)   = *(const float4*)(rc + 40 + d);
    *(float4*)(c2+4) = *(const float4*)(rc + 40 + d + 4);
    *(float4*)(s2)   = *(const float4*)(rc + 120 + d);
    *(float4*)(s2+4) = *(const float4*)(rc + 120 + d + 4);

    const float QS = 0.11180339887498949f * 1.4426950408889634f;
    bf16x8 r1, r2;
    #pragma unroll
    for (int i = 0; i < 8; ++i) {
        const float x1 = (float)x1v[i];
        const float x2 = (float)x2v[i];
        float o1 = x1 * c1[i] - x2 * s1[i];
        float o2 = x2 * c2[i] + x1 * s2[i];
        if (a == 0) { o1 *= QS; o2 *= QS; }
        r1[i] = (bf16)o1;
        r2[i] = (bf16)o2;
    }
    *(bf16x8*)(arr + base + d)      = r1;
    *(bf16x8*)(arr + base + 40 + d) = r2;
}

// ---------------------------------------------------------------------------
// Flash attention, swapped-operand form.
// T14 async-stage REWRITTEN: six NAMED float4 registers + straight-line
// macros (no arrays, no lambdas) — rule #20: address-taken arrays spilled
// to scratch last round (WRITE_SIZE 57 MB -> 1.05 GB smoking gun).
// Keeps: mask-only-last-tile, defer-max THR=8, setprio.
// ---------------------------------------------------------------------------
#define ATTN_ISSUE(ktp) do {                                                  \
    const long kro_ = qkbase + (long)(ktp)*64*HD;                             \
    kA = k0v ? *(const float4*)(kb + kro_ + (long)kr0*HD + kc0) : zero4;      \
    kB = k1v ? *(const float4*)(kb + kro_ + (long)kr1*HD + kc1) : zero4;      \
    kC = k2v ? *(const float4*)(kb + kro_ + (long)kr2*HD + kc2) : zero4;      \
    const long vro_ = vbase + (long)(ktp)*64 + vc8;                           \
    vA = *(const float4*)(vt + vro_ + (long)vd0*MAXP);                        \
    vB = *(const float4*)(vt + vro_ + (long)vd1*MAXP);                        \
    if (v2ok) vC = *(const float4*)(vt + vro_ + (long)vd2*MAXP);              \
} while (0)

#define ATTN_COMMIT() do {                                                    \
    *(float4*)(Ks + kr0*104 + kc0) = kA;                                      \
    *(float4*)(Ks + kr1*104 + kc1) = kB;                                      \
    *(float4*)(Ks + kr2*104 + kc2) = kC;                                      \
    *(float4*)(Vts + vd0*72 + vc8) = vA;                                      \
    *(float4*)(Vts + vd1*72 + vc8) = vB;                                      \
    if (v2ok) *(float4*)(Vts + vd2*72 + vc8) = vC;                            \
} while (0)

__global__ __launch_bounds__(256)
void attn_kernel(const bf16* __restrict__ qb, const bf16* __restrict__ kb,
                 const bf16* __restrict__ vt, const int* __restrict__ seq_lens,
                 bf16* __restrict__ outb)
{
    __shared__ __align__(16) bf16 Qs[64*104];    // stride 104 bf16 = 208 B
    __shared__ __align__(16) bf16 Ks[64*104];
    __shared__ __align__(16) bf16 Vts[80*72];    // V^T: [d][key], stride 144 B

    const int tid  = threadIdx.x;
    const int lane = tid & 63, wave = tid >> 6;
    const int quad = lane >> 4, c16 = lane & 15;
    const int qt = blockIdx.x, h = blockIdx.y, n = blockIdx.z;
    const int seqlen = seq_lens[n];

    const long qkbase = ((long)(n*NHEADS + h)) * MAXP * HD;
    const long vbase  = ((long)(n*NHEADS + h)) * HD * MAXP;

    const float4 zero4 = make_float4(0.f, 0.f, 0.f, 0.f);

    // staging geometry: K = 64 rows x 12 chunks (16B), V^T = 80 rows x 8 chunks
    const int kr0 = tid / 12,         kc0 = (tid % 12) * 8;
    const int kr1 = (tid + 256) / 12, kc1 = ((tid + 256) % 12) * 8;
    const int kr2 = (tid + 512) / 12, kc2 = ((tid + 512) % 12) * 8;
    const bool k0v = kc0 < 80, k1v = kc1 < 80, k2v = kc2 < 80;
    const int vd0 = tid >> 3, vd1 = vd0 + 32, vd2 = vd0 + 64;
    const int vc8 = (tid & 7) * 8;
    const bool v2ok = tid < 128;

    float4 kA, kB, kC, vA, vB, vC;

    // prologue: issue first K/V tile, stage Q
    ATTN_ISSUE(0);
    for (int i = tid; i < 768; i += 256) {       // 64 rows x 12 chunks of 16B
        int row = i / 12, c = i % 12;
        float4 v = (c < 10)
            ? *(const float4*)(qb + qkbase + (long)(qt*64 + row)*HD + c*8)
            : zero4;
        *(float4*)(Qs + row*104 + c*8) = v;
    }
    __syncthreads();
    bf16x8 aq[3];                                // Q as B-fragment (n = own q)
    #pragma unroll
    for (int kc = 0; kc < 3; ++kc)
        aq[kc] = *(const bf16x8*)(Qs + (wave*16 + c16)*104 + kc*32 + quad*8);

    float mrow = -1e30f, lrow = 0.0f;
    f32x4 O[5] = {};                             // O^T[d = dt*16+quad*4+r][q=c16]

    union U8 { bf16x8 v; bf16x4 h[2]; };

    const int nkt = (seqlen + 63) >> 6;
    for (int kt = 0; kt < nkt; ++kt) {
        __syncthreads();                         // prev tile's LDS reads done
        ATTN_COMMIT();
        __syncthreads();                         // LDS ready
        if (kt + 1 < nkt) ATTN_ISSUE(kt + 1);    // overlap next loads w/ compute

        // S^T = K * Q^T : A = K rows (m = key), B = Q (n = q)
        f32x4 S[4] = {};
        __builtin_amdgcn_s_setprio(1);
        #pragma unroll
        for (int kc = 0; kc < 3; ++kc) {
            const int ko = kc*32 + quad*8;
            #pragma unroll
            for (int nt = 0; nt < 4; ++nt) {
                bf16x8 ak = *(const bf16x8*)(Ks + (nt*16 + c16)*104 + ko);
                S[nt] = __builtin_amdgcn_mfma_f32_16x16x32_bf16(ak, aq[kc], S[nt], 0,0,0);
            }
        }
        __builtin_amdgcn_s_setprio(0);

        if (kt == nkt - 1) {                     // mask only on last tile
            #pragma unroll
            for (int nt = 0; nt < 4; ++nt) {
                const int key0 = kt*64 + nt*16 + quad*4;
                #pragma unroll
                for (int r = 0; r < 4; ++r)
                    if (key0 + r >= seqlen) S[nt][r] = -1e30f;
            }
        }

        // in-lane max tree (16 values) + 2 cross-quad shuffles
        float mx[4];
        #pragma unroll
        for (int nt = 0; nt < 4; ++nt)
            mx[nt] = fmaxf(fmaxf(S[nt][0], S[nt][1]), fmaxf(S[nt][2], S[nt][3]));
        float pmax = fmaxf(fmaxf(mx[0], mx[1]), fmaxf(mx[2], mx[3]));
        pmax = fmaxf(pmax, __shfl_xor(pmax, 16));
        pmax = fmaxf(pmax, __shfl_xor(pmax, 32));

        // T13 defer-max: only rescale when the max grew past mrow+8
        if (!__all(pmax <= mrow + 8.0f)) {
            const float nm    = fmaxf(mrow, pmax);
            const float alpha = exp2f(mrow - nm);
            mrow = nm;
            lrow *= alpha;
            #pragma unroll
            for (int dt = 0; dt < 5; ++dt)
                #pragma unroll
                for (int r = 0; r < 4; ++r)
                    O[dt][r] *= alpha;
        }

        #pragma unroll
        for (int nt = 0; nt < 4; ++nt)
            #pragma unroll
            for (int r = 0; r < 4; ++r)
                S[nt][r] = exp2f(S[nt][r] - mrow);

        float sm[4];
        #pragma unroll
        for (int nt = 0; nt < 4; ++nt)
            sm[nt] = (S[nt][0] + S[nt][1]) + (S[nt][2] + S[nt][3]);
        float rs = (sm[0] + sm[1]) + (sm[2] + sm[3]);
        rs += __shfl_xor(rs, 16);
        rs += __shfl_xor(rs, 32);
        lrow += rs;

        // pack P (lane-local): B-frag for PV kc = [pf[2kc][0..3], pf[2kc+1][0..3]]
        bf16x8 Pk[2];
        #pragma unroll
        for (int nt = 0; nt < 4; ++nt)
            #pragma unroll
            for (int r = 0; r < 4; ++r)
                Pk[nt >> 1][(nt & 1)*4 + r] = (bf16)S[nt][r];

        // O^T += V^T * P^T with key order kappa(kc,quad,j)
        __builtin_amdgcn_s_setprio(1);
        #pragma unroll
        for (int kc = 0; kc < 2; ++kc) {
            #pragma unroll
            for (int dt = 0; dt < 5; ++dt) {
                U8 av;
                av.h[0] = *(const bf16x4*)(Vts + (dt*16 + c16)*72 + kc*32 + quad*4);
                av.h[1] = *(const bf16x4*)(Vts + (dt*16 + c16)*72 + kc*32 + 16 + quad*4);
                O[dt] = __builtin_amdgcn_mfma_f32_16x16x32_bf16(av.v, Pk[kc], O[dt], 0,0,0);
            }
        }
        __builtin_amdgcn_s_setprio(0);
    }

    // epilogue: normalize, transpose O^T -> O through Qs (dead), coalesced store
    const float inv = 1.0f / lrow;
    #pragma unroll
    for (int dt = 0; dt < 5; ++dt)
        #pragma unroll
        for (int r = 0; r < 4; ++r)
            Qs[(wave*16 + c16)*104 + dt*16 + quad*4 + r] = (bf16)(O[dt][r] * inv);
    __syncthreads();
    for (int i = tid; i < 640; i += 256) {       // 64 rows x 10 chunks of 16B
        const int row = i / 10, c = i % 10;
        const float4 v = *(const float4*)(Qs + row*104 + c*8);
        *(float4*)(outb + ((long)(n*MAXP + qt*64 + row))*DIM + h*HD + c*8) = v;
    }
}

// ---------------------------------------------------------------------------
// Buffer plan:
//   d_ws   : hidden_bf (42 MB) | wqkv_bf (9.8 MB) | wproj_bf (3.3 MB)
//   d_out  : q (42 MB bf16) | k (42 MB bf16)  — overwritten by proj fp32 at end
//   d_in[0]: vT (42 MB bf16) | attn_out (42 MB bf16) — hidden fp32 dead after cvt
// ---------------------------------------------------------------------------
extern "C" void kernel_launch(void* const* d_in, const int* in_sizes, int n_in,
                              void* d_out, int out_size, void* d_ws, size_t ws_size,
                              hipStream_t stream)
{
    const float* hidden = (const float*)d_in[0];
    const float* rope   = (const float*)d_in[1];
    const int*   seql   = (const int*)d_in[2];
    const float* wqkv   = (const float*)d_in[3];
    const float* bqkv   = (const float*)d_in[4];
    const float* wproj  = (const float*)d_in[5];
    const float* bproj  = (const float*)d_in[6];
    float* out = (float*)d_out;

    const size_t H_ELEMS  = (size_t)MTOT*DIM;          // 20,971,520
    const size_t WQ_ELEMS = (size_t)3*DIM*DIM;         //  4,915,200
    const size_t WP_ELEMS = (size_t)DIM*DIM;           //  1,638,400
    const size_t QK_ELEMS = (size_t)NV*NHEADS*MAXP*HD; // 20,971,520

    bf16* h_bf  = (bf16*)d_ws;
    bf16* wq_bf = h_bf  + H_ELEMS;
    bf16* wp_bf = wq_bf + WQ_ELEMS;

    bf16* q_b = (bf16*)d_out;
    bf16* k_b = q_b + QK_ELEMS;
    bf16* v_t = (bf16*)d_in[0];
    bf16* a_b = v_t + QK_ELEMS;

    cvt_bf16<<<(H_ELEMS/4 + 255)/256, 256, 0, stream>>>(hidden, h_bf, H_ELEMS/4);
    cvt_bf16<<<(WQ_ELEMS/4 + 255)/256, 256, 0, stream>>>(wqkv, wq_bf, WQ_ELEMS/4);
    cvt_bf16<<<(WP_ELEMS/4 + 255)/256, 256, 0, stream>>>(wproj, wp_bf, WP_ELEMS/4);

    // QKV: grid = 8 XCD * 16 mb * 30 nb = 3840 ; G=6 (B group 1.9 MB in L2)
    gemm_nt_big<true, 30, 6><<<3840, 256, 0, stream>>>(
        h_bf, wq_bf, bqkv, q_b, k_b, v_t, nullptr);

    // rows = 2*16*16*1024 = 524288 ; 64 rows/block, 320 threads
    rope_kernel<<<524288/64, 320, 0, stream>>>(q_b, k_b, rope);

    attn_kernel<<<dim3(MAXP/64, NHEADS, NV), 256, 0, stream>>>(
        q_b, k_b, v_t, seql, a_b);

    // proj: grid = 8 * 16 * 10 = 1280 ; G=10 (whole wproj 3.3 MB in L2)
    gemm_nt_big<false, 10, 10><<<1280, 256, 0, stream>>>(
        a_b, wp_bf, bproj, nullptr, nullptr, nullptr, out);
}

// Round 5
// 607.598 us; speedup vs baseline: 1.4659x; 1.0817x over previous
//
#include <hip/hip_runtime.h>
#include <stdint.h>

#define DIM     1280
#define NHEADS  16
#define HD      80
#define NV      16
#define MAXP    1024
#define MTOT    (NV*MAXP)   // 16384

typedef __bf16 bf16;
using bf16x8 = __attribute__((ext_vector_type(8))) __bf16;
using bf16x4 = __attribute__((ext_vector_type(4))) __bf16;
using f32x4  = __attribute__((ext_vector_type(4))) float;

#define GLOAD_LDS16(g, l)                                                     \
    __builtin_amdgcn_global_load_lds(                                         \
        (const __attribute__((address_space(1))) void*)(g),                   \
        (__attribute__((address_space(3))) void*)(l), 16, 0, 0)

// ---------------------------------------------------------------------------
// fp32 -> bf16 bulk convert (vectorized, n must be a multiple of 4)
// ---------------------------------------------------------------------------
__global__ __launch_bounds__(256)
void cvt_bf16(const float* __restrict__ src, bf16* __restrict__ dst, int n4)
{
    const int i = blockIdx.x * 256 + threadIdx.x;
    if (i < n4) {
        const float4 f = ((const float4*)src)[i];
        bf16x4 r;
        r[0] = (bf16)f.x; r[1] = (bf16)f.y; r[2] = (bf16)f.z; r[3] = (bf16)f.w;
        ((bf16x4*)dst)[i] = r;
    }
}

// ---------------------------------------------------------------------------
// NT GEMM, XOR-swizzled LDS + XCD-chunked swizzle. NEW this round:
//   - double-buffered K-loop (T3-minimum / m139): issue next tile's 8
//     global_load_lds into the other buffer, s_waitcnt vmcnt(8) (older 8
//     only), raw s_barrier (no vmcnt(0) drain), compute, barrier.
//     Loads stay in flight across the whole compute phase.
//   - q/k epilogue staged through LDS: 8x bf16x8 stores per thread instead
//     of 64x 2B scatter.
// ---------------------------------------------------------------------------
#define GEMM_STAGE(dA, dB, koff) do {                                         \
    GLOAD_LDS16(ga[0] + (koff), (dA) + (0*4 + wave)*512);                     \
    GLOAD_LDS16(gb[0] + (koff), (dB) + (0*4 + wave)*512);                     \
    GLOAD_LDS16(ga[1] + (koff), (dA) + (1*4 + wave)*512);                     \
    GLOAD_LDS16(gb[1] + (koff), (dB) + (1*4 + wave)*512);                     \
    GLOAD_LDS16(ga[2] + (koff), (dA) + (2*4 + wave)*512);                     \
    GLOAD_LDS16(gb[2] + (koff), (dB) + (2*4 + wave)*512);                     \
    GLOAD_LDS16(ga[3] + (koff), (dA) + (3*4 + wave)*512);                     \
    GLOAD_LDS16(gb[3] + (koff), (dB) + (3*4 + wave)*512);                     \
} while (0)

template<bool IS_QKV, int NB, int G>
__global__ __launch_bounds__(256)
void gemm_nt_big(const bf16* __restrict__ A, const bf16* __restrict__ B,
                 const float* __restrict__ bias,
                 bf16* __restrict__ out0, bf16* __restrict__ out1,
                 bf16* __restrict__ out2, float* __restrict__ outf)
{
    const int K = DIM;
    const int NKT = K/64;                         // 20
    __shared__ __align__(16) bf16 SH[4*128*64];   // 64 KB: dbuf A|B ; C-stage
    bf16* const As0 = SH;
    bf16* const Bs0 = SH + 8192;
    bf16* const As1 = SH + 16384;
    bf16* const Bs1 = SH + 24576;

    const int tid  = threadIdx.x;
    const int lane = tid & 63, wave = tid >> 6;
    const int quad = lane >> 4, c16 = lane & 15;
    const int wm = wave & 1, wn = wave >> 1;

    // XCD-chunked block swizzle (bijective: grid = 8 * 16 * NB)
    const int bid = blockIdx.x;
    const int xcd = bid & 7;
    const int idx = bid >> 3;
    const int nbg = idx / (16*G);
    const int rem = idx % (16*G);
    const int mb  = xcd*16 + rem / G;
    const int nb  = nbg*G  + rem % G;

    const int sr   = lane >> 3;
    const int slot = lane & 7;
    const int sc   = (slot ^ sr) * 8;
    const long a_row0 = (long)mb * 128;
    const long b_row0 = (long)nb * 128;

    const bf16* ga[4];
    const bf16* gb[4];
    #pragma unroll
    for (int c = 0; c < 4; ++c) {
        const int seg = c*4 + wave;
        const int row = seg*8 + sr;
        ga[c] = A + (a_row0 + row)*K + sc;
        gb[c] = B + (b_row0 + row)*K + sc;
    }

    f32x4 acc[4][4] = {};
    const int xr = c16 & 7;

    GEMM_STAGE(As0, Bs0, 0);                      // prologue: tile 0 in flight

    for (int kt = 0; kt < NKT; ++kt) {
        const bool odd = kt & 1;
        bf16* const Ac = odd ? As1 : As0;
        bf16* const Bc = odd ? Bs1 : Bs0;
        if (kt + 1 < NKT) {
            bf16* const An = odd ? As0 : As1;
            bf16* const Bn = odd ? Bs0 : Bs1;
            GEMM_STAGE(An, Bn, (kt+1)*64);        // next tile: other buffer
            asm volatile("s_waitcnt vmcnt(8)" ::: "memory");  // old 8 done
        } else {
            asm volatile("s_waitcnt vmcnt(0)" ::: "memory");
        }
        __builtin_amdgcn_sched_barrier(0);
        __builtin_amdgcn_s_barrier();             // all waves: buf[kt] ready
        __builtin_amdgcn_sched_barrier(0);

        #pragma unroll
        for (int kk = 0; kk < 2; ++kk) {
            const int j  = kk*4 + quad;
            const int ko = ((j ^ xr) * 8);
            bf16x8 af[4], bfr[4];
            #pragma unroll
            for (int mt = 0; mt < 4; ++mt)
                af[mt] = *(const bf16x8*)(Ac + (wm*64 + mt*16 + c16)*64 + ko);
            #pragma unroll
            for (int nt = 0; nt < 4; ++nt)
                bfr[nt] = *(const bf16x8*)(Bc + (wn*64 + nt*16 + c16)*64 + ko);
            #pragma unroll
            for (int mt = 0; mt < 4; ++mt)
                #pragma unroll
                for (int nt = 0; nt < 4; ++nt)
                    acc[mt][nt] = __builtin_amdgcn_mfma_f32_16x16x32_bf16(
                        af[mt], bfr[nt], acc[mt][nt], 0, 0, 0);
        }

        __builtin_amdgcn_sched_barrier(0);
        __builtin_amdgcn_s_barrier();             // reads done before overwrite
        __builtin_amdgcn_sched_barrier(0);
    }

    if constexpr (IS_QKV) {
        const int which = nb / 10;               // block-uniform (q|k|v)
        if (which < 2) {
            // q/k: stage C-tile into LDS (chunk-XOR swizzle), then 16B stores.
            #pragma unroll
            for (int nt = 0; nt < 4; ++nt) {
                const int col = wn*64 + nt*16 + c16;          // local 0..127
                const float bv = bias[nb*128 + col];
                #pragma unroll
                for (int mt = 0; mt < 4; ++mt) {
                    #pragma unroll
                    for (int r = 0; r < 4; ++r) {
                        const int row = wm*64 + mt*16 + quad*4 + r;
                        SH[row*128 + (col ^ ((row & 7) << 3))] =
                            (bf16)(acc[mt][nt][r] + bv);
                    }
                }
            }
            __syncthreads();
            bf16* const dst = (which == 0) ? out0 : out1;
            const int n_ = mb >> 3;
            const int pb = (mb & 7) * 128;
            const int j  = tid & 15;
            const int colg = nb*128 - which*DIM + j*8;        // 0..1279
            const int hh = colg / 80;
            const int dd = colg - hh*80;
            #pragma unroll
            for (int i = 0; i < 8; ++i) {
                const int p = (tid >> 4) + 16*i;
                bf16x8 v = *(const bf16x8*)(SH + p*128 + ((j ^ (p & 7)) * 8));
                *(bf16x8*)(dst + ((long)((n_*NHEADS + hh)*MAXP + pb + p))*HD + dd) = v;
            }
        } else {
            // v^T: stage C-tile into LDS as VT[d][p ^ ((d&15)<<3)], then
            // coalesced 16B stores along p.
            #pragma unroll
            for (int nt = 0; nt < 4; ++nt) {
                const int dl0 = wn*64 + nt*16 + c16;          // local d 0..127
                const float bv = bias[nb*128 + dl0];
                const int swz = (dl0 & 15) << 3;
                #pragma unroll
                for (int mt = 0; mt < 4; ++mt) {
                    #pragma unroll
                    for (int r = 0; r < 4; ++r) {
                        const int pl = wm*64 + mt*16 + quad*4 + r;
                        SH[dl0*128 + (pl ^ swz)] = (bf16)(acc[mt][nt][r] + bv);
                    }
                }
            }
            __syncthreads();
            const int n_    = mb >> 3;
            const int pbase = (mb & 7) * 128;
            #pragma unroll
            for (int it = 0; it < 8; ++it) {
                const int c  = tid + 256*it;     // 0..2047
                const int dl = c >> 4, j = c & 15;
                const int p0 = (j ^ (dl & 15)) << 3;
                const int rr = (nb - 20)*128 + dl;
                const int hh = rr / HD;
                const int dd = rr - hh*HD;
                bf16x8 v = *(const bf16x8*)(SH + dl*128 + j*8);
                *(bf16x8*)(out2 + ((long)((n_*NHEADS + hh)*HD + dd))*MAXP
                                  + pbase + p0) = v;
            }
        }
    } else {
        #pragma unroll
        for (int nt = 0; nt < 4; ++nt) {
            const int col = nb*128 + wn*64 + nt*16 + c16;
            const float bv = bias[col];
            #pragma unroll
            for (int mt = 0; mt < 4; ++mt) {
                #pragma unroll
                for (int r = 0; r < 4; ++r) {
                    const int row = mb*128 + wm*64 + mt*16 + quad*4 + r;
                    outf[(long)row*DIM + col] = acc[mt][nt][r] + bv;
                }
            }
        }
    }
}

// ---------------------------------------------------------------------------
// RoPE in-place on q,k — vectorized (unchanged this round)
// ---------------------------------------------------------------------------
__global__ __launch_bounds__(320)
void rope_kernel(bf16* __restrict__ qb, bf16* __restrict__ kb,
                 const float* __restrict__ rope)
{
    const int tid = threadIdx.x;
    const int j   = tid % 5;
    const int rl  = tid / 5;
    const long grow = (long)blockIdx.x * 64 + rl;
    const int p = (int)(grow & 1023);
    const int h = (int)((grow >> 10) & 15);
    const int n = (int)((grow >> 14) & 15);
    const int a = (int)(grow >> 18);
    bf16* const arr = a ? kb : qb;
    const long base = ((long)((n*NHEADS + h)*MAXP + p))*HD;
    const float* rc = rope + ((long)(n*MAXP + p))*160;
    const int d = j*8;

    bf16x8 x1v = *(const bf16x8*)(arr + base + d);
    bf16x8 x2v = *(const bf16x8*)(arr + base + 40 + d);

    float c1[8], s1[8], c2[8], s2[8];
    *(float4*)(c1)   = *(const float4*)(rc + d);
    *(float4*)(c1+4) = *(const float4*)(rc + d + 4);
    *(float4*)(s1)   = *(const float4*)(rc + 80 + d);
    *(float4*)(s1+4) = *(const float4*)(rc + 80 + d + 4);
    *(float4*)(c2)   = *(const float4*)(rc + 40 + d);
    *(float4*)(c2+4) = *(const float4*)(rc + 40 + d + 4);
    *(float4*)(s2)   = *(const float4*)(rc + 120 + d);
    *(float4*)(s2+4) = *(const float4*)(rc + 120 + d + 4);

    const float QS = 0.11180339887498949f * 1.4426950408889634f;
    bf16x8 r1, r2;
    #pragma unroll
    for (int i = 0; i < 8; ++i) {
        const float x1 = (float)x1v[i];
        const float x2 = (float)x2v[i];
        float o1 = x1 * c1[i] - x2 * s1[i];
        float o2 = x2 * c2[i] + x1 * s2[i];
        if (a == 0) { o1 *= QS; o2 *= QS; }
        r1[i] = (bf16)o1;
        r2[i] = (bf16)o2;
    }
    *(bf16x8*)(arr + base + d)      = r1;
    *(bf16x8*)(arr + base + 40 + d) = r2;
}

// ---------------------------------------------------------------------------
// Flash attention, swapped-operand form (unchanged this round).
// ---------------------------------------------------------------------------
#define ATTN_ISSUE(ktp) do {                                                  \
    const long kro_ = qkbase + (long)(ktp)*64*HD;                             \
    kA = k0v ? *(const float4*)(kb + kro_ + (long)kr0*HD + kc0) : zero4;      \
    kB = k1v ? *(const float4*)(kb + kro_ + (long)kr1*HD + kc1) : zero4;      \
    kC = k2v ? *(const float4*)(kb + kro_ + (long)kr2*HD + kc2) : zero4;      \
    const long vro_ = vbase + (long)(ktp)*64 + vc8;                           \
    vA = *(const float4*)(vt + vro_ + (long)vd0*MAXP);                        \
    vB = *(const float4*)(vt + vro_ + (long)vd1*MAXP);                        \
    if (v2ok) vC = *(const float4*)(vt + vro_ + (long)vd2*MAXP);              \
} while (0)

#define ATTN_COMMIT() do {                                                    \
    *(float4*)(Ks + kr0*104 + kc0) = kA;                                      \
    *(float4*)(Ks + kr1*104 + kc1) = kB;                                      \
    *(float4*)(Ks + kr2*104 + kc2) = kC;                                      \
    *(float4*)(Vts + vd0*72 + vc8) = vA;                                      \
    *(float4*)(Vts + vd1*72 + vc8) = vB;                                      \
    if (v2ok) *(float4*)(Vts + vd2*72 + vc8) = vC;                            \
} while (0)

__global__ __launch_bounds__(256)
void attn_kernel(const bf16* __restrict__ qb, const bf16* __restrict__ kb,
                 const bf16* __restrict__ vt, const int* __restrict__ seq_lens,
                 bf16* __restrict__ outb)
{
    __shared__ __align__(16) bf16 Qs[64*104];    // stride 104 bf16 = 208 B
    __shared__ __align__(16) bf16 Ks[64*104];
    __shared__ __align__(16) bf16 Vts[80*72];    // V^T: [d][key], stride 144 B

    const int tid  = threadIdx.x;
    const int lane = tid & 63, wave = tid >> 6;
    const int quad = lane >> 4, c16 = lane & 15;
    const int qt = blockIdx.x, h = blockIdx.y, n = blockIdx.z;
    const int seqlen = seq_lens[n];

    const long qkbase = ((long)(n*NHEADS + h)) * MAXP * HD;
    const long vbase  = ((long)(n*NHEADS + h)) * HD * MAXP;

    const float4 zero4 = make_float4(0.f, 0.f, 0.f, 0.f);

    // staging geometry: K = 64 rows x 12 chunks (16B), V^T = 80 rows x 8 chunks
    const int kr0 = tid / 12,         kc0 = (tid % 12) * 8;
    const int kr1 = (tid + 256) / 12, kc1 = ((tid + 256) % 12) * 8;
    const int kr2 = (tid + 512) / 12, kc2 = ((tid + 512) % 12) * 8;
    const bool k0v = kc0 < 80, k1v = kc1 < 80, k2v = kc2 < 80;
    const int vd0 = tid >> 3, vd1 = vd0 + 32, vd2 = vd0 + 64;
    const int vc8 = (tid & 7) * 8;
    const bool v2ok = tid < 128;

    float4 kA, kB, kC, vA, vB, vC;

    // prologue: issue first K/V tile, stage Q
    ATTN_ISSUE(0);
    for (int i = tid; i < 768; i += 256) {       // 64 rows x 12 chunks of 16B
        int row = i / 12, c = i % 12;
        float4 v = (c < 10)
            ? *(const float4*)(qb + qkbase + (long)(qt*64 + row)*HD + c*8)
            : zero4;
        *(float4*)(Qs + row*104 + c*8) = v;
    }
    __syncthreads();
    bf16x8 aq[3];                                // Q as B-fragment (n = own q)
    #pragma unroll
    for (int kc = 0; kc < 3; ++kc)
        aq[kc] = *(const bf16x8*)(Qs + (wave*16 + c16)*104 + kc*32 + quad*8);

    float mrow = -1e30f, lrow = 0.0f;
    f32x4 O[5] = {};                             // O^T[d = dt*16+quad*4+r][q=c16]

    union U8 { bf16x8 v; bf16x4 h[2]; };

    const int nkt = (seqlen + 63) >> 6;
    for (int kt = 0; kt < nkt; ++kt) {
        __syncthreads();                         // prev tile's LDS reads done
        ATTN_COMMIT();
        __syncthreads();                         // LDS ready
        if (kt + 1 < nkt) ATTN_ISSUE(kt + 1);    // overlap next loads w/ compute

        // S^T = K * Q^T : A = K rows (m = key), B = Q (n = q)
        f32x4 S[4] = {};
        __builtin_amdgcn_s_setprio(1);
        #pragma unroll
        for (int kc = 0; kc < 3; ++kc) {
            const int ko = kc*32 + quad*8;
            #pragma unroll
            for (int nt = 0; nt < 4; ++nt) {
                bf16x8 ak = *(const bf16x8*)(Ks + (nt*16 + c16)*104 + ko);
                S[nt] = __builtin_amdgcn_mfma_f32_16x16x32_bf16(ak, aq[kc], S[nt], 0,0,0);
            }
        }
        __builtin_amdgcn_s_setprio(0);

        if (kt == nkt - 1) {                     // mask only on last tile
            #pragma unroll
            for (int nt = 0; nt < 4; ++nt) {
                const int key0 = kt*64 + nt*16 + quad*4;
                #pragma unroll
                for (int r = 0; r < 4; ++r)
                    if (key0 + r >= seqlen) S[nt][r] = -1e30f;
            }
        }

        // in-lane max tree (16 values) + 2 cross-quad shuffles
        float mx[4];
        #pragma unroll
        for (int nt = 0; nt < 4; ++nt)
            mx[nt] = fmaxf(fmaxf(S[nt][0], S[nt][1]), fmaxf(S[nt][2], S[nt][3]));
        float pmax = fmaxf(fmaxf(mx[0], mx[1]), fmaxf(mx[2], mx[3]));
        pmax = fmaxf(pmax, __shfl_xor(pmax, 16));
        pmax = fmaxf(pmax, __shfl_xor(pmax, 32));

        // T13 defer-max: only rescale when the max grew past mrow+8
        if (!__all(pmax <= mrow + 8.0f)) {
            const float nm    = fmaxf(mrow, pmax);
            const float alpha = exp2f(mrow - nm);
            mrow = nm;
            lrow *= alpha;
            #pragma unroll
            for (int dt = 0; dt < 5; ++dt)
                #pragma unroll
                for (int r = 0; r < 4; ++r)
                    O[dt][r] *= alpha;
        }

        #pragma unroll
        for (int nt = 0; nt < 4; ++nt)
            #pragma unroll
            for (int r = 0; r < 4; ++r)
                S[nt][r] = exp2f(S[nt][r] - mrow);

        float sm[4];
        #pragma unroll
        for (int nt = 0; nt < 4; ++nt)
            sm[nt] = (S[nt][0] + S[nt][1]) + (S[nt][2] + S[nt][3]);
        float rs = (sm[0] + sm[1]) + (sm[2] + sm[3]);
        rs += __shfl_xor(rs, 16);
        rs += __shfl_xor(rs, 32);
        lrow += rs;

        // pack P (lane-local): B-frag for PV kc = [pf[2kc][0..3], pf[2kc+1][0..3]]
        bf16x8 Pk[2];
        #pragma unroll
        for (int nt = 0; nt < 4; ++nt)
            #pragma unroll
            for (int r = 0; r < 4; ++r)
                Pk[nt >> 1][(nt & 1)*4 + r] = (bf16)S[nt][r];

        // O^T += V^T * P^T with key order kappa(kc,quad,j)
        __builtin_amdgcn_s_setprio(1);
        #pragma unroll
        for (int kc = 0; kc < 2; ++kc) {
            #pragma unroll
            for (int dt = 0; dt < 5; ++dt) {
                U8 av;
                av.h[0] = *(const bf16x4*)(Vts + (dt*16 + c16)*72 + kc*32 + quad*4);
                av.h[1] = *(const bf16x4*)(Vts + (dt*16 + c16)*72 + kc*32 + 16 + quad*4);
                O[dt] = __builtin_amdgcn_mfma_f32_16x16x32_bf16(av.v, Pk[kc], O[dt], 0,0,0);
            }
        }
        __builtin_amdgcn_s_setprio(0);
    }

    // epilogue: normalize, transpose O^T -> O through Qs (dead), coalesced store
    const float inv = 1.0f / lrow;
    #pragma unroll
    for (int dt = 0; dt < 5; ++dt)
        #pragma unroll
        for (int r = 0; r < 4; ++r)
            Qs[(wave*16 + c16)*104 + dt*16 + quad*4 + r] = (bf16)(O[dt][r] * inv);
    __syncthreads();
    for (int i = tid; i < 640; i += 256) {       // 64 rows x 10 chunks of 16B
        const int row = i / 10, c = i % 10;
        const float4 v = *(const float4*)(Qs + row*104 + c*8);
        *(float4*)(outb + ((long)(n*MAXP + qt*64 + row))*DIM + h*HD + c*8) = v;
    }
}

// ---------------------------------------------------------------------------
// Buffer plan:
//   d_ws   : hidden_bf (42 MB) | wqkv_bf (9.8 MB) | wproj_bf (3.3 MB)
//   d_out  : q (42 MB bf16) | k (42 MB bf16)  — overwritten by proj fp32 at end
//   d_in[0]: vT (42 MB bf16) | attn_out (42 MB bf16) — hidden fp32 dead after cvt
// ---------------------------------------------------------------------------
extern "C" void kernel_launch(void* const* d_in, const int* in_sizes, int n_in,
                              void* d_out, int out_size, void* d_ws, size_t ws_size,
                              hipStream_t stream)
{
    const float* hidden = (const float*)d_in[0];
    const float* rope   = (const float*)d_in[1];
    const int*   seql   = (const int*)d_in[2];
    const float* wqkv   = (const float*)d_in[3];
    const float* bqkv   = (const float*)d_in[4];
    const float* wproj  = (const float*)d_in[5];
    const float* bproj  = (const float*)d_in[6];
    float* out = (float*)d_out;

    const size_t H_ELEMS  = (size_t)MTOT*DIM;          // 20,971,520
    const size_t WQ_ELEMS = (size_t)3*DIM*DIM;         //  4,915,200
    const size_t WP_ELEMS = (size_t)DIM*DIM;           //  1,638,400
    const size_t QK_ELEMS = (size_t)NV*NHEADS*MAXP*HD; // 20,971,520

    bf16* h_bf  = (bf16*)d_ws;
    bf16* wq_bf = h_bf  + H_ELEMS;
    bf16* wp_bf = wq_bf + WQ_ELEMS;

    bf16* q_b = (bf16*)d_out;
    bf16* k_b = q_b + QK_ELEMS;
    bf16* v_t = (bf16*)d_in[0];
    bf16* a_b = v_t + QK_ELEMS;

    cvt_bf16<<<(H_ELEMS/4 + 255)/256, 256, 0, stream>>>(hidden, h_bf, H_ELEMS/4);
    cvt_bf16<<<(WQ_ELEMS/4 + 255)/256, 256, 0, stream>>>(wqkv, wq_bf, WQ_ELEMS/4);
    cvt_bf16<<<(WP_ELEMS/4 + 255)/256, 256, 0, stream>>>(wproj, wp_bf, WP_ELEMS/4);

    // QKV: grid = 8 XCD * 16 mb * 30 nb = 3840 ; G=6 (B group 1.9 MB in L2)
    gemm_nt_big<true, 30, 6><<<3840, 256, 0, stream>>>(
        h_bf, wq_bf, bqkv, q_b, k_b, v_t, nullptr);

    // rows = 2*16*16*1024 = 524288 ; 64 rows/block, 320 threads
    rope_kernel<<<524288/64, 320, 0, stream>>>(q_b, k_b, rope);

    attn_kernel<<<dim3(MAXP/64, NHEADS, NV), 256, 0, stream>>>(
        q_b, k_b, v_t, seql, a_b);

    // proj: grid = 8 * 16 * 10 = 1280 ; G=10 (whole wproj 3.3 MB in L2)
    gemm_nt_big<false, 10, 10><<<1280, 256, 0, stream>>>(
        a_b, wp_bf, bproj, nullptr, nullptr, nullptr, out);
}

// Round 6
// 593.617 us; speedup vs baseline: 1.5004x; 1.0236x over previous
//
#include <hip/hip_runtime.h>
#include <stdint.h>

#define DIM     1280
#define NHEADS  16
#define HD      80
#define NV      16
#define MAXP    1024
#define MTOT    (NV*MAXP)   // 16384

typedef __bf16 bf16;
using bf16x8 = __attribute__((ext_vector_type(8))) __bf16;
using bf16x4 = __attribute__((ext_vector_type(4))) __bf16;
using f32x4  = __attribute__((ext_vector_type(4))) float;

#define GLOAD_LDS16(g, l)                                                     \
    __builtin_amdgcn_global_load_lds(                                         \
        (const __attribute__((address_space(1))) void*)(g),                   \
        (__attribute__((address_space(3))) void*)(l), 16, 0, 0)

// ---------------------------------------------------------------------------
// fp32 -> bf16 bulk convert (vectorized, n must be a multiple of 4)
// ---------------------------------------------------------------------------
__global__ __launch_bounds__(256)
void cvt_bf16(const float* __restrict__ src, bf16* __restrict__ dst, int n4)
{
    const int i = blockIdx.x * 256 + threadIdx.x;
    if (i < n4) {
        const float4 f = ((const float4*)src)[i];
        bf16x4 r;
        r[0] = (bf16)f.x; r[1] = (bf16)f.y; r[2] = (bf16)f.z; r[3] = (bf16)f.w;
        ((bf16x4*)dst)[i] = r;
    }
}

// ---------------------------------------------------------------------------
// NT GEMM, XOR-swizzled LDS + XCD-chunked swizzle + double-buffered K-loop
// with counted vmcnt. (unchanged this round)
// ---------------------------------------------------------------------------
#define GEMM_STAGE(dA, dB, koff) do {                                         \
    GLOAD_LDS16(ga[0] + (koff), (dA) + (0*4 + wave)*512);                     \
    GLOAD_LDS16(gb[0] + (koff), (dB) + (0*4 + wave)*512);                     \
    GLOAD_LDS16(ga[1] + (koff), (dA) + (1*4 + wave)*512);                     \
    GLOAD_LDS16(gb[1] + (koff), (dB) + (1*4 + wave)*512);                     \
    GLOAD_LDS16(ga[2] + (koff), (dA) + (2*4 + wave)*512);                     \
    GLOAD_LDS16(gb[2] + (koff), (dB) + (2*4 + wave)*512);                     \
    GLOAD_LDS16(ga[3] + (koff), (dA) + (3*4 + wave)*512);                     \
    GLOAD_LDS16(gb[3] + (koff), (dB) + (3*4 + wave)*512);                     \
} while (0)

template<bool IS_QKV, int NB, int G>
__global__ __launch_bounds__(256)
void gemm_nt_big(const bf16* __restrict__ A, const bf16* __restrict__ B,
                 const float* __restrict__ bias,
                 bf16* __restrict__ out0, bf16* __restrict__ out1,
                 bf16* __restrict__ out2, float* __restrict__ outf)
{
    const int K = DIM;
    const int NKT = K/64;                         // 20
    __shared__ __align__(16) bf16 SH[4*128*64];   // 64 KB: dbuf A|B ; C-stage
    bf16* const As0 = SH;
    bf16* const Bs0 = SH + 8192;
    bf16* const As1 = SH + 16384;
    bf16* const Bs1 = SH + 24576;

    const int tid  = threadIdx.x;
    const int lane = tid & 63, wave = tid >> 6;
    const int quad = lane >> 4, c16 = lane & 15;
    const int wm = wave & 1, wn = wave >> 1;

    // XCD-chunked block swizzle (bijective: grid = 8 * 16 * NB)
    const int bid = blockIdx.x;
    const int xcd = bid & 7;
    const int idx = bid >> 3;
    const int nbg = idx / (16*G);
    const int rem = idx % (16*G);
    const int mb  = xcd*16 + rem / G;
    const int nb  = nbg*G  + rem % G;

    const int sr   = lane >> 3;
    const int slot = lane & 7;
    const int sc   = (slot ^ sr) * 8;
    const long a_row0 = (long)mb * 128;
    const long b_row0 = (long)nb * 128;

    const bf16* ga[4];
    const bf16* gb[4];
    #pragma unroll
    for (int c = 0; c < 4; ++c) {
        const int seg = c*4 + wave;
        const int row = seg*8 + sr;
        ga[c] = A + (a_row0 + row)*K + sc;
        gb[c] = B + (b_row0 + row)*K + sc;
    }

    f32x4 acc[4][4] = {};
    const int xr = c16 & 7;

    GEMM_STAGE(As0, Bs0, 0);                      // prologue: tile 0 in flight

    for (int kt = 0; kt < NKT; ++kt) {
        const bool odd = kt & 1;
        bf16* const Ac = odd ? As1 : As0;
        bf16* const Bc = odd ? Bs1 : Bs0;
        if (kt + 1 < NKT) {
            bf16* const An = odd ? As0 : As1;
            bf16* const Bn = odd ? Bs0 : Bs1;
            GEMM_STAGE(An, Bn, (kt+1)*64);        // next tile: other buffer
            asm volatile("s_waitcnt vmcnt(8)" ::: "memory");  // old 8 done
        } else {
            asm volatile("s_waitcnt vmcnt(0)" ::: "memory");
        }
        __builtin_amdgcn_sched_barrier(0);
        __builtin_amdgcn_s_barrier();             // all waves: buf[kt] ready
        __builtin_amdgcn_sched_barrier(0);

        #pragma unroll
        for (int kk = 0; kk < 2; ++kk) {
            const int j  = kk*4 + quad;
            const int ko = ((j ^ xr) * 8);
            bf16x8 af[4], bfr[4];
            #pragma unroll
            for (int mt = 0; mt < 4; ++mt)
                af[mt] = *(const bf16x8*)(Ac + (wm*64 + mt*16 + c16)*64 + ko);
            #pragma unroll
            for (int nt = 0; nt < 4; ++nt)
                bfr[nt] = *(const bf16x8*)(Bc + (wn*64 + nt*16 + c16)*64 + ko);
            #pragma unroll
            for (int mt = 0; mt < 4; ++mt)
                #pragma unroll
                for (int nt = 0; nt < 4; ++nt)
                    acc[mt][nt] = __builtin_amdgcn_mfma_f32_16x16x32_bf16(
                        af[mt], bfr[nt], acc[mt][nt], 0, 0, 0);
        }

        __builtin_amdgcn_sched_barrier(0);
        __builtin_amdgcn_s_barrier();             // reads done before overwrite
        __builtin_amdgcn_sched_barrier(0);
    }

    if constexpr (IS_QKV) {
        const int which = nb / 10;               // block-uniform (q|k|v)
        if (which < 2) {
            // q/k: stage C-tile into LDS (chunk-XOR swizzle), then 16B stores.
            #pragma unroll
            for (int nt = 0; nt < 4; ++nt) {
                const int col = wn*64 + nt*16 + c16;          // local 0..127
                const float bv = bias[nb*128 + col];
                #pragma unroll
                for (int mt = 0; mt < 4; ++mt) {
                    #pragma unroll
                    for (int r = 0; r < 4; ++r) {
                        const int row = wm*64 + mt*16 + quad*4 + r;
                        SH[row*128 + (col ^ ((row & 7) << 3))] =
                            (bf16)(acc[mt][nt][r] + bv);
                    }
                }
            }
            __syncthreads();
            bf16* const dst = (which == 0) ? out0 : out1;
            const int n_ = mb >> 3;
            const int pb = (mb & 7) * 128;
            const int j  = tid & 15;
            const int colg = nb*128 - which*DIM + j*8;        // 0..1279
            const int hh = colg / 80;
            const int dd = colg - hh*80;
            #pragma unroll
            for (int i = 0; i < 8; ++i) {
                const int p = (tid >> 4) + 16*i;
                bf16x8 v = *(const bf16x8*)(SH + p*128 + ((j ^ (p & 7)) * 8));
                *(bf16x8*)(dst + ((long)((n_*NHEADS + hh)*MAXP + pb + p))*HD + dd) = v;
            }
        } else {
            // v^T: stage C-tile into LDS as VT[d][p ^ ((d&15)<<3)], then
            // coalesced 16B stores along p.
            #pragma unroll
            for (int nt = 0; nt < 4; ++nt) {
                const int dl0 = wn*64 + nt*16 + c16;          // local d 0..127
                const float bv = bias[nb*128 + dl0];
                const int swz = (dl0 & 15) << 3;
                #pragma unroll
                for (int mt = 0; mt < 4; ++mt) {
                    #pragma unroll
                    for (int r = 0; r < 4; ++r) {
                        const int pl = wm*64 + mt*16 + quad*4 + r;
                        SH[dl0*128 + (pl ^ swz)] = (bf16)(acc[mt][nt][r] + bv);
                    }
                }
            }
            __syncthreads();
            const int n_    = mb >> 3;
            const int pbase = (mb & 7) * 128;
            #pragma unroll
            for (int it = 0; it < 8; ++it) {
                const int c  = tid + 256*it;     // 0..2047
                const int dl = c >> 4, j = c & 15;
                const int p0 = (j ^ (dl & 15)) << 3;
                const int rr = (nb - 20)*128 + dl;
                const int hh = rr / HD;
                const int dd = rr - hh*HD;
                bf16x8 v = *(const bf16x8*)(SH + dl*128 + j*8);
                *(bf16x8*)(out2 + ((long)((n_*NHEADS + hh)*HD + dd))*MAXP
                                  + pbase + p0) = v;
            }
        }
    } else {
        #pragma unroll
        for (int nt = 0; nt < 4; ++nt) {
            const int col = nb*128 + wn*64 + nt*16 + c16;
            const float bv = bias[col];
            #pragma unroll
            for (int mt = 0; mt < 4; ++mt) {
                #pragma unroll
                for (int r = 0; r < 4; ++r) {
                    const int row = mb*128 + wm*64 + mt*16 + quad*4 + r;
                    outf[(long)row*DIM + col] = acc[mt][nt][r] + bv;
                }
            }
        }
    }
}

// ---------------------------------------------------------------------------
// RoPE in-place on q,k — vectorized (unchanged this round)
// ---------------------------------------------------------------------------
__global__ __launch_bounds__(320)
void rope_kernel(bf16* __restrict__ qb, bf16* __restrict__ kb,
                 const float* __restrict__ rope)
{
    const int tid = threadIdx.x;
    const int j   = tid % 5;
    const int rl  = tid / 5;
    const long grow = (long)blockIdx.x * 64 + rl;
    const int p = (int)(grow & 1023);
    const int h = (int)((grow >> 10) & 15);
    const int n = (int)((grow >> 14) & 15);
    const int a = (int)(grow >> 18);
    bf16* const arr = a ? kb : qb;
    const long base = ((long)((n*NHEADS + h)*MAXP + p))*HD;
    const float* rc = rope + ((long)(n*MAXP + p))*160;
    const int d = j*8;

    bf16x8 x1v = *(const bf16x8*)(arr + base + d);
    bf16x8 x2v = *(const bf16x8*)(arr + base + 40 + d);

    float c1[8], s1[8], c2[8], s2[8];
    *(float4*)(c1)   = *(const float4*)(rc + d);
    *(float4*)(c1+4) = *(const float4*)(rc + d + 4);
    *(float4*)(s1)   = *(const float4*)(rc + 80 + d);
    *(float4*)(s1+4) = *(const float4*)(rc + 80 + d + 4);
    *(float4*)(c2)   = *(const float4*)(rc + 40 + d);
    *(float4*)(c2+4) = *(const float4*)(rc + 40 + d + 4);
    *(float4*)(s2)   = *(const float4*)(rc + 120 + d);
    *(float4*)(s2+4) = *(const float4*)(rc + 120 + d + 4);

    const float QS = 0.11180339887498949f * 1.4426950408889634f;
    bf16x8 r1, r2;
    #pragma unroll
    for (int i = 0; i < 8; ++i) {
        const float x1 = (float)x1v[i];
        const float x2 = (float)x2v[i];
        float o1 = x1 * c1[i] - x2 * s1[i];
        float o2 = x2 * c2[i] + x1 * s2[i];
        if (a == 0) { o1 *= QS; o2 *= QS; }
        r1[i] = (bf16)o1;
        r2[i] = (bf16)o2;
    }
    *(bf16x8*)(arr + base + d)      = r1;
    *(bf16x8*)(arr + base + 40 + d) = r2;
}

// ---------------------------------------------------------------------------
// Flash attention, swapped-operand form. NEW this round:
//   - Vts stride 72 -> 68 bf16 (34 dwords ≡ 2 mod 32): PV b64 reads and
//     commit writes become bank-conflict-free (was 2x serialization —
//     SQ_LDS_BANK_CONFLICT 2.78e7 ≈ 23% of runtime). Commit uses 2x 8B
//     writes (136B rows are 8B- but not 16B-aligned).
//   - Qs buffer eliminated: Q loaded global->regs directly (one-time);
//     epilogue transposes through Ks (dead after the loop, barrier added).
//     LDS 38.4 KB -> 24.2 KB => 6 blocks/CU (was 3-4).
// ---------------------------------------------------------------------------
#define ATTN_ISSUE(ktp) do {                                                  \
    const long kro_ = qkbase + (long)(ktp)*64*HD;                             \
    kA = k0v ? *(const float4*)(kb + kro_ + (long)kr0*HD + kc0) : zero4;      \
    kB = k1v ? *(const float4*)(kb + kro_ + (long)kr1*HD + kc1) : zero4;      \
    kC = k2v ? *(const float4*)(kb + kro_ + (long)kr2*HD + kc2) : zero4;      \
    const long vro_ = vbase + (long)(ktp)*64 + vc8;                           \
    vA = *(const float4*)(vt + vro_ + (long)vd0*MAXP);                        \
    vB = *(const float4*)(vt + vro_ + (long)vd1*MAXP);                        \
    if (v2ok) vC = *(const float4*)(vt + vro_ + (long)vd2*MAXP);              \
} while (0)

#define ATTN_COMMIT() do {                                                    \
    *(float4*)(Ks + kr0*104 + kc0) = kA;                                      \
    *(float4*)(Ks + kr1*104 + kc1) = kB;                                      \
    *(float4*)(Ks + kr2*104 + kc2) = kC;                                      \
    *(float2*)(Vts + vd0*68 + vc8)     = make_float2(vA.x, vA.y);             \
    *(float2*)(Vts + vd0*68 + vc8 + 4) = make_float2(vA.z, vA.w);             \
    *(float2*)(Vts + vd1*68 + vc8)     = make_float2(vB.x, vB.y);             \
    *(float2*)(Vts + vd1*68 + vc8 + 4) = make_float2(vB.z, vB.w);             \
    if (v2ok) {                                                               \
        *(float2*)(Vts + vd2*68 + vc8)     = make_float2(vC.x, vC.y);         \
        *(float2*)(Vts + vd2*68 + vc8 + 4) = make_float2(vC.z, vC.w);         \
    }                                                                         \
} while (0)

__global__ __launch_bounds__(256)
void attn_kernel(const bf16* __restrict__ qb, const bf16* __restrict__ kb,
                 const bf16* __restrict__ vt, const int* __restrict__ seq_lens,
                 bf16* __restrict__ outb)
{
    __shared__ __align__(16) bf16 Ks[64*104];    // stride 104 bf16 = 208 B
    __shared__ __align__(16) bf16 Vts[80*68];    // V^T: [d][key], stride 136 B

    const int tid  = threadIdx.x;
    const int lane = tid & 63, wave = tid >> 6;
    const int quad = lane >> 4, c16 = lane & 15;
    const int qt = blockIdx.x, h = blockIdx.y, n = blockIdx.z;
    const int seqlen = seq_lens[n];

    const long qkbase = ((long)(n*NHEADS + h)) * MAXP * HD;
    const long vbase  = ((long)(n*NHEADS + h)) * HD * MAXP;

    const float4 zero4 = make_float4(0.f, 0.f, 0.f, 0.f);

    // staging geometry: K = 64 rows x 12 chunks (16B), V^T = 80 rows x 8 chunks
    const int kr0 = tid / 12,         kc0 = (tid % 12) * 8;
    const int kr1 = (tid + 256) / 12, kc1 = ((tid + 256) % 12) * 8;
    const int kr2 = (tid + 512) / 12, kc2 = ((tid + 512) % 12) * 8;
    const bool k0v = kc0 < 80, k1v = kc1 < 80, k2v = kc2 < 80;
    const int vd0 = tid >> 3, vd1 = vd0 + 32, vd2 = vd0 + 64;
    const int vc8 = (tid & 7) * 8;
    const bool v2ok = tid < 128;

    float4 kA, kB, kC, vA, vB, vC;

    // prologue: issue first K/V tile; Q straight into registers
    ATTN_ISSUE(0);
    bf16x8 aq[3];                                // Q as B-fragment (n = own q)
    {
        const bf16* qrow = qb + qkbase + (long)(qt*64 + wave*16 + c16)*HD + quad*8;
        aq[0] = *(const bf16x8*)(qrow);
        aq[1] = *(const bf16x8*)(qrow + 32);
        aq[2] = *(const bf16x8*)(qrow + 64);
    }

    float mrow = -1e30f, lrow = 0.0f;
    f32x4 O[5] = {};                             // O^T[d = dt*16+quad*4+r][q=c16]

    union U8 { bf16x8 v; bf16x4 h[2]; };

    const int nkt = (seqlen + 63) >> 6;
    for (int kt = 0; kt < nkt; ++kt) {
        __syncthreads();                         // prev tile's LDS reads done
        ATTN_COMMIT();
        __syncthreads();                         // LDS ready
        if (kt + 1 < nkt) ATTN_ISSUE(kt + 1);    // overlap next loads w/ compute

        // S^T = K * Q^T : A = K rows (m = key), B = Q (n = q)
        f32x4 S[4] = {};
        __builtin_amdgcn_s_setprio(1);
        #pragma unroll
        for (int kc = 0; kc < 3; ++kc) {
            const int ko = kc*32 + quad*8;
            #pragma unroll
            for (int nt = 0; nt < 4; ++nt) {
                bf16x8 ak = *(const bf16x8*)(Ks + (nt*16 + c16)*104 + ko);
                S[nt] = __builtin_amdgcn_mfma_f32_16x16x32_bf16(ak, aq[kc], S[nt], 0,0,0);
            }
        }
        __builtin_amdgcn_s_setprio(0);

        if (kt == nkt - 1) {                     // mask only on last tile
            #pragma unroll
            for (int nt = 0; nt < 4; ++nt) {
                const int key0 = kt*64 + nt*16 + quad*4;
                #pragma unroll
                for (int r = 0; r < 4; ++r)
                    if (key0 + r >= seqlen) S[nt][r] = -1e30f;
            }
        }

        // in-lane max tree (16 values) + 2 cross-quad shuffles
        float mx[4];
        #pragma unroll
        for (int nt = 0; nt < 4; ++nt)
            mx[nt] = fmaxf(fmaxf(S[nt][0], S[nt][1]), fmaxf(S[nt][2], S[nt][3]));
        float pmax = fmaxf(fmaxf(mx[0], mx[1]), fmaxf(mx[2], mx[3]));
        pmax = fmaxf(pmax, __shfl_xor(pmax, 16));
        pmax = fmaxf(pmax, __shfl_xor(pmax, 32));

        // T13 defer-max: only rescale when the max grew past mrow+8
        if (!__all(pmax <= mrow + 8.0f)) {
            const float nm    = fmaxf(mrow, pmax);
            const float alpha = exp2f(mrow - nm);
            mrow = nm;
            lrow *= alpha;
            #pragma unroll
            for (int dt = 0; dt < 5; ++dt)
                #pragma unroll
                for (int r = 0; r < 4; ++r)
                    O[dt][r] *= alpha;
        }

        #pragma unroll
        for (int nt = 0; nt < 4; ++nt)
            #pragma unroll
            for (int r = 0; r < 4; ++r)
                S[nt][r] = exp2f(S[nt][r] - mrow);

        float sm[4];
        #pragma unroll
        for (int nt = 0; nt < 4; ++nt)
            sm[nt] = (S[nt][0] + S[nt][1]) + (S[nt][2] + S[nt][3]);
        float rs = (sm[0] + sm[1]) + (sm[2] + sm[3]);
        rs += __shfl_xor(rs, 16);
        rs += __shfl_xor(rs, 32);
        lrow += rs;

        // pack P (lane-local): B-frag for PV kc = [pf[2kc][0..3], pf[2kc+1][0..3]]
        bf16x8 Pk[2];
        #pragma unroll
        for (int nt = 0; nt < 4; ++nt)
            #pragma unroll
            for (int r = 0; r < 4; ++r)
                Pk[nt >> 1][(nt & 1)*4 + r] = (bf16)S[nt][r];

        // O^T += V^T * P^T with key order kappa(kc,quad,j)
        __builtin_amdgcn_s_setprio(1);
        #pragma unroll
        for (int kc = 0; kc < 2; ++kc) {
            #pragma unroll
            for (int dt = 0; dt < 5; ++dt) {
                U8 av;
                av.h[0] = *(const bf16x4*)(Vts + (dt*16 + c16)*68 + kc*32 + quad*4);
                av.h[1] = *(const bf16x4*)(Vts + (dt*16 + c16)*68 + kc*32 + 16 + quad*4);
                O[dt] = __builtin_amdgcn_mfma_f32_16x16x32_bf16(av.v, Pk[kc], O[dt], 0,0,0);
            }
        }
        __builtin_amdgcn_s_setprio(0);
    }

    // epilogue: normalize, transpose O^T -> O through Ks (dead), coalesced store
    __syncthreads();                             // all waves done reading Ks
    const float inv = 1.0f / lrow;
    #pragma unroll
    for (int dt = 0; dt < 5; ++dt)
        #pragma unroll
        for (int r = 0; r < 4; ++r)
            Ks[(wave*16 + c16)*104 + dt*16 + quad*4 + r] = (bf16)(O[dt][r] * inv);
    __syncthreads();
    for (int i = tid; i < 640; i += 256) {       // 64 rows x 10 chunks of 16B
        const int row = i / 10, c = i % 10;
        const float4 v = *(const float4*)(Ks + row*104 + c*8);
        *(float4*)(outb + ((long)(n*MAXP + qt*64 + row))*DIM + h*HD + c*8) = v;
    }
}

// ---------------------------------------------------------------------------
// Buffer plan:
//   d_ws   : hidden_bf (42 MB) | wqkv_bf (9.8 MB) | wproj_bf (3.3 MB)
//   d_out  : q (42 MB bf16) | k (42 MB bf16)  — overwritten by proj fp32 at end
//   d_in[0]: vT (42 MB bf16) | attn_out (42 MB bf16) — hidden fp32 dead after cvt
// ---------------------------------------------------------------------------
extern "C" void kernel_launch(void* const* d_in, const int* in_sizes, int n_in,
                              void* d_out, int out_size, void* d_ws, size_t ws_size,
                              hipStream_t stream)
{
    const float* hidden = (const float*)d_in[0];
    const float* rope   = (const float*)d_in[1];
    const int*   seql   = (const int*)d_in[2];
    const float* wqkv   = (const float*)d_in[3];
    const float* bqkv   = (const float*)d_in[4];
    const float* wproj  = (const float*)d_in[5];
    const float* bproj  = (const float*)d_in[6];
    float* out = (float*)d_out;

    const size_t H_ELEMS  = (size_t)MTOT*DIM;          // 20,971,520
    const size_t WQ_ELEMS = (size_t)3*DIM*DIM;         //  4,915,200
    const size_t WP_ELEMS = (size_t)DIM*DIM;           //  1,638,400
    const size_t QK_ELEMS = (size_t)NV*NHEADS*MAXP*HD; // 20,971,520

    bf16* h_bf  = (bf16*)d_ws;
    bf16* wq_bf = h_bf  + H_ELEMS;
    bf16* wp_bf = wq_bf + WQ_ELEMS;

    bf16* q_b = (bf16*)d_out;
    bf16* k_b = q_b + QK_ELEMS;
    bf16* v_t = (bf16*)d_in[0];
    bf16* a_b = v_t + QK_ELEMS;

    cvt_bf16<<<(H_ELEMS/4 + 255)/256, 256, 0, stream>>>(hidden, h_bf, H_ELEMS/4);
    cvt_bf16<<<(WQ_ELEMS/4 + 255)/256, 256, 0, stream>>>(wqkv, wq_bf, WQ_ELEMS/4);
    cvt_bf16<<<(WP_ELEMS/4 + 255)/256, 256, 0, stream>>>(wproj, wp_bf, WP_ELEMS/4);

    // QKV: grid = 8 XCD * 16 mb * 30 nb = 3840 ; G=6 (B group 1.9 MB in L2)
    gemm_nt_big<true, 30, 6><<<3840, 256, 0, stream>>>(
        h_bf, wq_bf, bqkv, q_b, k_b, v_t, nullptr);

    // rows = 2*16*16*1024 = 524288 ; 64 rows/block, 320 threads
    rope_kernel<<<524288/64, 320, 0, stream>>>(q_b, k_b, rope);

    attn_kernel<<<dim3(MAXP/64, NHEADS, NV), 256, 0, stream>>>(
        q_b, k_b, v_t, seql, a_b);

    // proj: grid = 8 * 16 * 10 = 1280 ; G=10 (whole wproj 3.3 MB in L2)
    gemm_nt_big<false, 10, 10><<<1280, 256, 0, stream>>>(
        a_b, wp_bf, bproj, nullptr, nullptr, nullptr, out);
}

// Round 8
// 556.719 us; speedup vs baseline: 1.5998x; 1.0663x over previous
//
#include <hip/hip_runtime.h>
#include <stdint.h>

#define DIM     1280
#define NHEADS  16
#define HD      80
#define NV      16
#define MAXP    1024
#define MTOT    (NV*MAXP)   // 16384

typedef __bf16 bf16;
using bf16x8 = __attribute__((ext_vector_type(8))) __bf16;
using bf16x4 = __attribute__((ext_vector_type(4))) __bf16;
using f32x4  = __attribute__((ext_vector_type(4))) float;

#define GLOAD_LDS16(g, l)                                                     \
    __builtin_amdgcn_global_load_lds(                                         \
        (const __attribute__((address_space(1))) void*)(g),                   \
        (__attribute__((address_space(3))) void*)(l), 16, 0, 0)

// ---------------------------------------------------------------------------
// fp32 -> bf16 bulk convert (vectorized, n must be a multiple of 4)
// ---------------------------------------------------------------------------
__global__ __launch_bounds__(256)
void cvt_bf16(const float* __restrict__ src, bf16* __restrict__ dst, int n4)
{
    const int i = blockIdx.x * 256 + threadIdx.x;
    if (i < n4) {
        const float4 f = ((const float4*)src)[i];
        bf16x4 r;
        r[0] = (bf16)f.x; r[1] = (bf16)f.y; r[2] = (bf16)f.z; r[3] = (bf16)f.w;
        ((bf16x4*)dst)[i] = r;
    }
}

// ---------------------------------------------------------------------------
// NT GEMM, XOR-swizzled LDS + XCD-chunked swizzle + double-buffered K-loop
// with counted vmcnt. (unchanged)
// ---------------------------------------------------------------------------
#define GEMM_STAGE(dA, dB, koff) do {                                         \
    GLOAD_LDS16(ga[0] + (koff), (dA) + (0*4 + wave)*512);                     \
    GLOAD_LDS16(gb[0] + (koff), (dB) + (0*4 + wave)*512);                     \
    GLOAD_LDS16(ga[1] + (koff), (dA) + (1*4 + wave)*512);                     \
    GLOAD_LDS16(gb[1] + (koff), (dB) + (1*4 + wave)*512);                     \
    GLOAD_LDS16(ga[2] + (koff), (dA) + (2*4 + wave)*512);                     \
    GLOAD_LDS16(gb[2] + (koff), (dB) + (2*4 + wave)*512);                     \
    GLOAD_LDS16(ga[3] + (koff), (dA) + (3*4 + wave)*512);                     \
    GLOAD_LDS16(gb[3] + (koff), (dB) + (3*4 + wave)*512);                     \
} while (0)

template<bool IS_QKV, int NB, int G>
__global__ __launch_bounds__(256)
void gemm_nt_big(const bf16* __restrict__ A, const bf16* __restrict__ B,
                 const float* __restrict__ bias,
                 bf16* __restrict__ out0, bf16* __restrict__ out1,
                 bf16* __restrict__ out2, float* __restrict__ outf)
{
    const int K = DIM;
    const int NKT = K/64;                         // 20
    __shared__ __align__(16) bf16 SH[4*128*64];   // 64 KB: dbuf A|B ; C-stage
    bf16* const As0 = SH;
    bf16* const Bs0 = SH + 8192;
    bf16* const As1 = SH + 16384;
    bf16* const Bs1 = SH + 24576;

    const int tid  = threadIdx.x;
    const int lane = tid & 63, wave = tid >> 6;
    const int quad = lane >> 4, c16 = lane & 15;
    const int wm = wave & 1, wn = wave >> 1;

    // XCD-chunked block swizzle (bijective: grid = 8 * 16 * NB)
    const int bid = blockIdx.x;
    const int xcd = bid & 7;
    const int idx = bid >> 3;
    const int nbg = idx / (16*G);
    const int rem = idx % (16*G);
    const int mb  = xcd*16 + rem / G;
    const int nb  = nbg*G  + rem % G;

    const int sr   = lane >> 3;
    const int slot = lane & 7;
    const int sc   = (slot ^ sr) * 8;
    const long a_row0 = (long)mb * 128;
    const long b_row0 = (long)nb * 128;

    const bf16* ga[4];
    const bf16* gb[4];
    #pragma unroll
    for (int c = 0; c < 4; ++c) {
        const int seg = c*4 + wave;
        const int row = seg*8 + sr;
        ga[c] = A + (a_row0 + row)*K + sc;
        gb[c] = B + (b_row0 + row)*K + sc;
    }

    f32x4 acc[4][4] = {};
    const int xr = c16 & 7;

    GEMM_STAGE(As0, Bs0, 0);                      // prologue: tile 0 in flight

    for (int kt = 0; kt < NKT; ++kt) {
        const bool odd = kt & 1;
        bf16* const Ac = odd ? As1 : As0;
        bf16* const Bc = odd ? Bs1 : Bs0;
        if (kt + 1 < NKT) {
            bf16* const An = odd ? As0 : As1;
            bf16* const Bn = odd ? Bs0 : Bs1;
            GEMM_STAGE(An, Bn, (kt+1)*64);        // next tile: other buffer
            asm volatile("s_waitcnt vmcnt(8)" ::: "memory");  // old 8 done
        } else {
            asm volatile("s_waitcnt vmcnt(0)" ::: "memory");
        }
        __builtin_amdgcn_sched_barrier(0);
        __builtin_amdgcn_s_barrier();             // all waves: buf[kt] ready
        __builtin_amdgcn_sched_barrier(0);

        #pragma unroll
        for (int kk = 0; kk < 2; ++kk) {
            const int j  = kk*4 + quad;
            const int ko = ((j ^ xr) * 8);
            bf16x8 af[4], bfr[4];
            #pragma unroll
            for (int mt = 0; mt < 4; ++mt)
                af[mt] = *(const bf16x8*)(Ac + (wm*64 + mt*16 + c16)*64 + ko);
            #pragma unroll
            for (int nt = 0; nt < 4; ++nt)
                bfr[nt] = *(const bf16x8*)(Bc + (wn*64 + nt*16 + c16)*64 + ko);
            #pragma unroll
            for (int mt = 0; mt < 4; ++mt)
                #pragma unroll
                for (int nt = 0; nt < 4; ++nt)
                    acc[mt][nt] = __builtin_amdgcn_mfma_f32_16x16x32_bf16(
                        af[mt], bfr[nt], acc[mt][nt], 0, 0, 0);
        }

        __builtin_amdgcn_sched_barrier(0);
        __builtin_amdgcn_s_barrier();             // reads done before overwrite
        __builtin_amdgcn_sched_barrier(0);
    }

    if constexpr (IS_QKV) {
        const int which = nb / 10;               // block-uniform (q|k|v)
        if (which < 2) {
            // q/k: stage C-tile into LDS (chunk-XOR swizzle), then 16B stores.
            #pragma unroll
            for (int nt = 0; nt < 4; ++nt) {
                const int col = wn*64 + nt*16 + c16;          // local 0..127
                const float bv = bias[nb*128 + col];
                #pragma unroll
                for (int mt = 0; mt < 4; ++mt) {
                    #pragma unroll
                    for (int r = 0; r < 4; ++r) {
                        const int row = wm*64 + mt*16 + quad*4 + r;
                        SH[row*128 + (col ^ ((row & 7) << 3))] =
                            (bf16)(acc[mt][nt][r] + bv);
                    }
                }
            }
            __syncthreads();
            bf16* const dst = (which == 0) ? out0 : out1;
            const int n_ = mb >> 3;
            const int pb = (mb & 7) * 128;
            const int j  = tid & 15;
            const int colg = nb*128 - which*DIM + j*8;        // 0..1279
            const int hh = colg / 80;
            const int dd = colg - hh*80;
            #pragma unroll
            for (int i = 0; i < 8; ++i) {
                const int p = (tid >> 4) + 16*i;
                bf16x8 v = *(const bf16x8*)(SH + p*128 + ((j ^ (p & 7)) * 8));
                *(bf16x8*)(dst + ((long)((n_*NHEADS + hh)*MAXP + pb + p))*HD + dd) = v;
            }
        } else {
            // v^T: stage C-tile into LDS as VT[d][p ^ ((d&15)<<3)], then
            // coalesced 16B stores along p.
            #pragma unroll
            for (int nt = 0; nt < 4; ++nt) {
                const int dl0 = wn*64 + nt*16 + c16;          // local d 0..127
                const float bv = bias[nb*128 + dl0];
                const int swz = (dl0 & 15) << 3;
                #pragma unroll
                for (int mt = 0; mt < 4; ++mt) {
                    #pragma unroll
                    for (int r = 0; r < 4; ++r) {
                        const int pl = wm*64 + mt*16 + quad*4 + r;
                        SH[dl0*128 + (pl ^ swz)] = (bf16)(acc[mt][nt][r] + bv);
                    }
                }
            }
            __syncthreads();
            const int n_    = mb >> 3;
            const int pbase = (mb & 7) * 128;
            #pragma unroll
            for (int it = 0; it < 8; ++it) {
                const int c  = tid + 256*it;     // 0..2047
                const int dl = c >> 4, j = c & 15;
                const int p0 = (j ^ (dl & 15)) << 3;
                const int rr = (nb - 20)*128 + dl;
                const int hh = rr / HD;
                const int dd = rr - hh*HD;
                bf16x8 v = *(const bf16x8*)(SH + dl*128 + j*8);
                *(bf16x8*)(out2 + ((long)((n_*NHEADS + hh)*HD + dd))*MAXP
                                  + pbase + p0) = v;
            }
        }
    } else {
        #pragma unroll
        for (int nt = 0; nt < 4; ++nt) {
            const int col = nb*128 + wn*64 + nt*16 + c16;
            const float bv = bias[col];
            #pragma unroll
            for (int mt = 0; mt < 4; ++mt) {
                #pragma unroll
                for (int r = 0; r < 4; ++r) {
                    const int row = mb*128 + wm*64 + mt*16 + quad*4 + r;
                    outf[(long)row*DIM + col] = acc[mt][nt][r] + bv;
                }
            }
        }
    }
}

// ---------------------------------------------------------------------------
// RoPE in-place on q,k — vectorized (unchanged)
// ---------------------------------------------------------------------------
__global__ __launch_bounds__(320)
void rope_kernel(bf16* __restrict__ qb, bf16* __restrict__ kb,
                 const float* __restrict__ rope)
{
    const int tid = threadIdx.x;
    const int j   = tid % 5;
    const int rl  = tid / 5;
    const long grow = (long)blockIdx.x * 64 + rl;
    const int p = (int)(grow & 1023);
    const int h = (int)((grow >> 10) & 15);
    const int n = (int)((grow >> 14) & 15);
    const int a = (int)(grow >> 18);
    bf16* const arr = a ? kb : qb;
    const long base = ((long)((n*NHEADS + h)*MAXP + p))*HD;
    const float* rc = rope + ((long)(n*MAXP + p))*160;
    const int d = j*8;

    bf16x8 x1v = *(const bf16x8*)(arr + base + d);
    bf16x8 x2v = *(const bf16x8*)(arr + base + 40 + d);

    float c1[8], s1[8], c2[8], s2[8];
    *(float4*)(c1)   = *(const float4*)(rc + d);
    *(float4*)(c1+4) = *(const float4*)(rc + d + 4);
    *(float4*)(s1)   = *(const float4*)(rc + 80 + d);
    *(float4*)(s1+4) = *(const float4*)(rc + 80 + d + 4);
    *(float4*)(c2)   = *(const float4*)(rc + 40 + d);
    *(float4*)(c2+4) = *(const float4*)(rc + 40 + d + 4);
    *(float4*)(s2)   = *(const float4*)(rc + 120 + d);
    *(float4*)(s2+4) = *(const float4*)(rc + 120 + d + 4);

    const float QS = 0.11180339887498949f * 1.4426950408889634f;
    bf16x8 r1, r2;
    #pragma unroll
    for (int i = 0; i < 8; ++i) {
        const float x1 = (float)x1v[i];
        const float x2 = (float)x2v[i];
        float o1 = x1 * c1[i] - x2 * s1[i];
        float o2 = x2 * c2[i] + x1 * s2[i];
        if (a == 0) { o1 *= QS; o2 *= QS; }
        r1[i] = (bf16)o1;
        r2[i] = (bf16)o2;
    }
    *(bf16x8*)(arr + base + d)      = r1;
    *(bf16x8*)(arr + base + 40 + d) = r2;
}

// ---------------------------------------------------------------------------
// Flash attention, swapped-operand form (same as round 6 — infra retry):
//   - QBLK 128, 8 waves / 512 threads; staging and barriers per q-row halved.
//   - ones-row lrow: Vts rows 80..95 = 1.0; 6th PV d-tile computes the
//     softmax denominator on the matrix pipe; O[5] rescales with alpha.
//   - epilogue transposes through SM overlay as [128][88].
// ---------------------------------------------------------------------------
#define ATTN_ISSUE(ktp) do {                                                  \
    const long kro_ = qkbase + (long)(ktp)*64*HD;                             \
    kA = k0v ? *(const float4*)(kb + kro_ + (long)kr0*HD + kc0) : zero4;      \
    if (k1on) kB = k1v ? *(const float4*)(kb + kro_ + (long)kr1*HD + kc1) : zero4; \
    const long vro_ = vbase + (long)(ktp)*64 + vc8;                           \
    vA = *(const float4*)(vt + vro_ + (long)vd0*MAXP);                        \
    if (v1on) vB = *(const float4*)(vt + vro_ + (long)vd1*MAXP);              \
} while (0)

#define ATTN_COMMIT() do {                                                    \
    *(float4*)(Ks + kr0*104 + kc0) = kA;                                      \
    if (k1on) *(float4*)(Ks + kr1*104 + kc1) = kB;                            \
    *(float2*)(Vts + vd0*68 + vc8)     = make_float2(vA.x, vA.y);             \
    *(float2*)(Vts + vd0*68 + vc8 + 4) = make_float2(vA.z, vA.w);             \
    if (v1on) {                                                               \
        *(float2*)(Vts + vd1*68 + vc8)     = make_float2(vB.x, vB.y);         \
        *(float2*)(Vts + vd1*68 + vc8 + 4) = make_float2(vB.z, vB.w);         \
    }                                                                         \
} while (0)

__global__ __launch_bounds__(512)
void attn_kernel(const bf16* __restrict__ qb, const bf16* __restrict__ kb,
                 const bf16* __restrict__ vt, const int* __restrict__ seq_lens,
                 bf16* __restrict__ outb)
{
    // SM overlay: Ks [64][104] | Vts [96][68] (rows 80..95 = ones);
    // epilogue reuses the whole thing as [128][88].
    __shared__ __align__(16) bf16 SM[64*104 + 96*68];   // 26368 B
    bf16* const Ks  = SM;
    bf16* const Vts = SM + 64*104;

    const int tid  = threadIdx.x;
    const int lane = tid & 63, wave = tid >> 6;          // wave 0..7
    const int quad = lane >> 4, c16 = lane & 15;
    const int qt = blockIdx.x, h = blockIdx.y, n = blockIdx.z;
    const int seqlen = seq_lens[n];

    const long qkbase = ((long)(n*NHEADS + h)) * MAXP * HD;
    const long vbase  = ((long)(n*NHEADS + h)) * HD * MAXP;

    const float4 zero4 = make_float4(0.f, 0.f, 0.f, 0.f);

    // staging geometry (512 threads): K = 64 rows x 12 chunks (768 slots),
    // V^T = 80 rows x 8 chunks (640 slots)
    const int kr0 = tid / 12,         kc0 = (tid % 12) * 8;
    const int kr1 = (tid + 512) / 12, kc1 = ((tid + 512) % 12) * 8;
    const bool k0v = kc0 < 80, k1v = kc1 < 80;
    const bool k1on = tid < 256;
    const int vd0 = tid >> 3, vd1 = vd0 + 64;
    const int vc8 = (tid & 7) * 8;
    const bool v1on = tid < 128;

    float4 kA, kB, vA, vB;

    // prologue: ones rows for the lrow MFMA; first K/V tile; Q into regs
    for (int i = tid; i < 16*68; i += 512)
        Vts[80*68 + i] = (bf16)1.0f;
    ATTN_ISSUE(0);
    bf16x8 aq[3];                                // Q as B-fragment (n = own q)
    {
        const bf16* qrow = qb + qkbase + (long)(qt*128 + wave*16 + c16)*HD + quad*8;
        aq[0] = *(const bf16x8*)(qrow);
        aq[1] = *(const bf16x8*)(qrow + 32);
        aq[2] = *(const bf16x8*)(qrow + 64);
    }

    float mrow = -1e30f;
    f32x4 O[6] = {};                 // O^T[d][q=c16]; O[5] = running row-sum

    union U8 { bf16x8 v; bf16x4 h[2]; };

    const int nkt = (seqlen + 63) >> 6;
    for (int kt = 0; kt < nkt; ++kt) {
        __syncthreads();                         // prev tile's LDS reads done
        ATTN_COMMIT();
        __syncthreads();                         // LDS ready (covers ones-init)
        if (kt + 1 < nkt) ATTN_ISSUE(kt + 1);    // overlap next loads w/ compute

        // S^T = K * Q^T : A = K rows (m = key), B = Q (n = q)
        f32x4 S[4] = {};
        __builtin_amdgcn_s_setprio(1);
        #pragma unroll
        for (int kc = 0; kc < 3; ++kc) {
            const int ko = kc*32 + quad*8;
            #pragma unroll
            for (int nt = 0; nt < 4; ++nt) {
                bf16x8 ak = *(const bf16x8*)(Ks + (nt*16 + c16)*104 + ko);
                S[nt] = __builtin_amdgcn_mfma_f32_16x16x32_bf16(ak, aq[kc], S[nt], 0,0,0);
            }
        }
        __builtin_amdgcn_s_setprio(0);

        if (kt == nkt - 1) {                     // mask only on last tile
            #pragma unroll
            for (int nt = 0; nt < 4; ++nt) {
                const int key0 = kt*64 + nt*16 + quad*4;
                #pragma unroll
                for (int r = 0; r < 4; ++r)
                    if (key0 + r >= seqlen) S[nt][r] = -1e30f;
            }
        }

        // in-lane max tree (16 values) + 2 cross-quad shuffles
        float mx[4];
        #pragma unroll
        for (int nt = 0; nt < 4; ++nt)
            mx[nt] = fmaxf(fmaxf(S[nt][0], S[nt][1]), fmaxf(S[nt][2], S[nt][3]));
        float pmax = fmaxf(fmaxf(mx[0], mx[1]), fmaxf(mx[2], mx[3]));
        pmax = fmaxf(pmax, __shfl_xor(pmax, 16));
        pmax = fmaxf(pmax, __shfl_xor(pmax, 32));

        // T13 defer-max: only rescale when the max grew past mrow+8
        if (!__all(pmax <= mrow + 8.0f)) {
            const float nm    = fmaxf(mrow, pmax);
            const float alpha = exp2f(mrow - nm);
            mrow = nm;
            #pragma unroll
            for (int dt = 0; dt < 6; ++dt)       // O[5] (=lrow) rescales too
                #pragma unroll
                for (int r = 0; r < 4; ++r)
                    O[dt][r] *= alpha;
        }

        #pragma unroll
        for (int nt = 0; nt < 4; ++nt)
            #pragma unroll
            for (int r = 0; r < 4; ++r)
                S[nt][r] = exp2f(S[nt][r] - mrow);

        // pack P (lane-local): B-frag for PV kc = [pf[2kc][0..3], pf[2kc+1][0..3]]
        bf16x8 Pk[2];
        #pragma unroll
        for (int nt = 0; nt < 4; ++nt)
            #pragma unroll
            for (int r = 0; r < 4; ++r)
                Pk[nt >> 1][(nt & 1)*4 + r] = (bf16)S[nt][r];

        // O^T += V^T * P^T with key order kappa(kc,quad,j); dt=5 = ones row
        __builtin_amdgcn_s_setprio(1);
        #pragma unroll
        for (int kc = 0; kc < 2; ++kc) {
            #pragma unroll
            for (int dt = 0; dt < 6; ++dt) {
                U8 av;
                av.h[0] = *(const bf16x4*)(Vts + (dt*16 + c16)*68 + kc*32 + quad*4);
                av.h[1] = *(const bf16x4*)(Vts + (dt*16 + c16)*68 + kc*32 + 16 + quad*4);
                O[dt] = __builtin_amdgcn_mfma_f32_16x16x32_bf16(av.v, Pk[kc], O[dt], 0,0,0);
            }
        }
        __builtin_amdgcn_s_setprio(0);
    }

    // epilogue: normalize by O[5][0] (= lrow, identical in all lanes' frags),
    // transpose O^T -> O through SM as [128][88], coalesced 16B stores.
    __syncthreads();                             // all waves done reading SM
    const float inv = 1.0f / O[5][0];
    #pragma unroll
    for (int dt = 0; dt < 5; ++dt)
        #pragma unroll
        for (int r = 0; r < 4; ++r)
            SM[(wave*16 + c16)*88 + dt*16 + quad*4 + r] = (bf16)(O[dt][r] * inv);
    __syncthreads();
    for (int i = tid; i < 1280; i += 512) {      // 128 rows x 10 chunks of 16B
        const int row = i / 10, c = i % 10;
        const float4 v = *(const float4*)(SM + row*88 + c*8);
        *(float4*)(outb + ((long)(n*MAXP + qt*128 + row))*DIM + h*HD + c*8) = v;
    }
}

// ---------------------------------------------------------------------------
// Buffer plan:
//   d_ws   : hidden_bf (42 MB) | wqkv_bf (9.8 MB) | wproj_bf (3.3 MB)
//   d_out  : q (42 MB bf16) | k (42 MB bf16)  — overwritten by proj fp32 at end
//   d_in[0]: vT (42 MB bf16) | attn_out (42 MB bf16) — hidden fp32 dead after cvt
// ---------------------------------------------------------------------------
extern "C" void kernel_launch(void* const* d_in, const int* in_sizes, int n_in,
                              void* d_out, int out_size, void* d_ws, size_t ws_size,
                              hipStream_t stream)
{
    const float* hidden = (const float*)d_in[0];
    const float* rope   = (const float*)d_in[1];
    const int*   seql   = (const int*)d_in[2];
    const float* wqkv   = (const float*)d_in[3];
    const float* bqkv   = (const float*)d_in[4];
    const float* wproj  = (const float*)d_in[5];
    const float* bproj  = (const float*)d_in[6];
    float* out = (float*)d_out;

    const size_t H_ELEMS  = (size_t)MTOT*DIM;          // 20,971,520
    const size_t WQ_ELEMS = (size_t)3*DIM*DIM;         //  4,915,200
    const size_t WP_ELEMS = (size_t)DIM*DIM;           //  1,638,400
    const size_t QK_ELEMS = (size_t)NV*NHEADS*MAXP*HD; // 20,971,520

    bf16* h_bf  = (bf16*)d_ws;
    bf16* wq_bf = h_bf  + H_ELEMS;
    bf16* wp_bf = wq_bf + WQ_ELEMS;

    bf16* q_b = (bf16*)d_out;
    bf16* k_b = q_b + QK_ELEMS;
    bf16* v_t = (bf16*)d_in[0];
    bf16* a_b = v_t + QK_ELEMS;

    cvt_bf16<<<(H_ELEMS/4 + 255)/256, 256, 0, stream>>>(hidden, h_bf, H_ELEMS/4);
    cvt_bf16<<<(WQ_ELEMS/4 + 255)/256, 256, 0, stream>>>(wqkv, wq_bf, WQ_ELEMS/4);
    cvt_bf16<<<(WP_ELEMS/4 + 255)/256, 256, 0, stream>>>(wproj, wp_bf, WP_ELEMS/4);

    // QKV: grid = 8 XCD * 16 mb * 30 nb = 3840 ; G=6 (B group 1.9 MB in L2)
    gemm_nt_big<true, 30, 6><<<3840, 256, 0, stream>>>(
        h_bf, wq_bf, bqkv, q_b, k_b, v_t, nullptr);

    // rows = 2*16*16*1024 = 524288 ; 64 rows/block, 320 threads
    rope_kernel<<<524288/64, 320, 0, stream>>>(q_b, k_b, rope);

    // QBLK=128: grid = (1024/128, 16, 16), 512 threads
    attn_kernel<<<dim3(MAXP/128, NHEADS, NV), 512, 0, stream>>>(
        q_b, k_b, v_t, seql, a_b);

    // proj: grid = 8 * 16 * 10 = 1280 ; G=10 (whole wproj 3.3 MB in L2)
    gemm_nt_big<false, 10, 10><<<1280, 256, 0, stream>>>(
        a_b, wp_bf, bproj, nullptr, nullptr, nullptr, out);
}